// Round 3
// baseline (552.253 us; speedup 1.0000x reference)
//
#include <hip/hip_runtime.h>
#include <math.h>

// GlobalLocalAttention — mask-sparse pipeline, GEMMs via bf16x2-split MFMA.
// R3: tap-major K + pre-split c-innermost f_ds  => corr staging is pure b128 ld/st.
//     softmax writes pre-split transposed P     => tgemm staging is pure b128 ld/st.

constexpr int B_ = 4, C_ = 128, D_ = 16;
constexpr int FH = 96, FW = 96;
constexpr int Hh = 48, Wd = 48;
constexpr int L_ = Hh * Wd;           // 2304
constexpr int NEED_CAP = 384, HOLE_CAP = 320;
constexpr int KC = C_ * 9;            // 1152
constexpr float SCALE_ = 10.0f;
constexpr float EPS_ = 1e-4f;

typedef __attribute__((ext_vector_type(8))) short bf16x8;
typedef __attribute__((ext_vector_type(4))) float f32x4;

static __device__ __forceinline__ f32x4 mfma16(bf16x8 a, bf16x8 b, f32x4 c) {
  return __builtin_amdgcn_mfma_f32_16x16x32_bf16(a, b, c, 0, 0, 0);
}
static __device__ __forceinline__ unsigned short bf16_rne(float f) {
  unsigned u = __builtin_bit_cast(unsigned, f);
  unsigned r = (u + 0x7FFFu + ((u >> 16) & 1u)) >> 16;
  return (unsigned short)r;
}
static __device__ __forceinline__ float bf16f(unsigned short h) {
  unsigned u = ((unsigned)h) << 16;
  return __builtin_bit_cast(float, u);
}
static __device__ __forceinline__ void split2(float v, unsigned short& hi, unsigned short& lo) {
  hi = bf16_rne(v);
  lo = bf16_rne(v - bf16f(hi));
}

constexpr size_t A256(size_t v) { return (v + 255) & ~size_t(255); }
constexpr size_t OFF_META  = 0;
constexpr size_t OFF_MDS   = A256(OFF_META + 64 * 4);
constexpr size_t OFF_MP    = A256(OFF_MDS + (size_t)L_ * 4);
constexpr size_t OFF_MM    = A256(OFF_MP + (size_t)L_ * 9 * 4);
constexpr size_t OFF_ROWL  = A256(OFF_MM + (size_t)L_ * 4);
constexpr size_t OFF_NLIST = A256(OFF_ROWL + (size_t)L_ * 4);
constexpr size_t OFF_HLIST = A256(OFF_NLIST + (size_t)NEED_CAP * 4);
constexpr size_t OFF_NS1   = A256(OFF_HLIST + (size_t)HOLE_CAP * 4);
constexpr size_t OFF_NRAW  = A256(OFF_NS1 + (size_t)L_ * 4);
constexpr size_t OFF_FDS   = A256(OFF_NRAW + (size_t)L_ * 4);                    // fp32 [B][C][48][48]
constexpr size_t OFF_BDS   = A256(OFF_FDS + (size_t)B_ * C_ * L_ * 4);
constexpr size_t OFF_FDSH  = A256(OFF_BDS + (size_t)B_ * C_ * L_ * 4);           // bf16 [B][pos][c]
constexpr size_t OFF_FDSL  = A256(OFF_FDSH + (size_t)B_ * L_ * C_ * 2);
constexpr size_t OFF_WNH   = A256(OFF_FDSL + (size_t)B_ * L_ * C_ * 2);          // bf16 [B][384][1152] tap-major k
constexpr size_t OFF_WNL   = A256(OFF_WNH + (size_t)B_ * NEED_CAP * KC * 2);
constexpr size_t OFF_SRAW  = A256(OFF_WNL + (size_t)B_ * NEED_CAP * KC * 2);     // fp32 [B][384][L]
constexpr size_t OFF_SF    = A256(OFF_SRAW + (size_t)B_ * NEED_CAP * L_ * 4);    // fp32 [B][320][L]
constexpr size_t OFF_PHT   = A256(OFF_SF + (size_t)B_ * HOLE_CAP * L_ * 4);      // bf16 [B][x][rh] transposed
constexpr size_t OFF_PLT   = A256(OFF_PHT + (size_t)B_ * L_ * HOLE_CAP * 2);
constexpr size_t OFF_RWH   = A256(OFF_PLT + (size_t)B_ * L_ * HOLE_CAP * 2);     // bf16 [2048][320]
constexpr size_t OFF_RWL   = A256(OFF_RWH + (size_t)2048 * HOLE_CAP * 2);
constexpr size_t OFF_T     = A256(OFF_RWL + (size_t)2048 * HOLE_CAP * 2);        // fp32 [2048][L]
// total ~80.6 MB (<= proven-available 81.1 MB)

// ---------------- mask prep + compaction ----------------
__global__ __launch_bounds__(256) void gla_prep(const float* __restrict__ mask, char* __restrict__ ws)
{
  float* m_ds = (float*)(ws + OFF_MDS);
  float* m_p  = (float*)(ws + OFF_MP);
  float* mm   = (float*)(ws + OFF_MM);
  int* row_l  = (int*)(ws + OFF_ROWL);
  int* nlist  = (int*)(ws + OFF_NLIST);
  int* hlist  = (int*)(ws + OFF_HLIST);
  int* ns1    = (int*)(ws + OFF_NS1);
  int* nraw   = (int*)(ws + OFF_NRAW);
  int* meta   = (int*)(ws + OFF_META);
  const int t = threadIdx.x;

  for (int l = t; l < L_; l += 256) {
    int y = l / Wd, x = l % Wd;
    m_ds[l] = mask[(size_t)(8 * y) * 384 + 8 * x];
  }
  __syncthreads();
  for (int l = t; l < L_; l += 256) {
    int y = l / Wd, x = l % Wd;
    bool all0 = true;
    for (int dy = 0; dy < 3; dy++)
      for (int dx = 0; dx < 3; dx++) {
        int sy = y + dy - 1, sx = x + dx - 1;
        float v = ((unsigned)sy < (unsigned)Hh && (unsigned)sx < (unsigned)Wd) ? m_ds[sy * Wd + sx] : 0.f;
        m_p[l * 9 + dy * 3 + dx] = v;
        if (v != 0.f) all0 = false;
      }
    mm[l] = all0 ? 1.f : 0.f;
    ns1[l] = 0; nraw[l] = 0; row_l[l] = -1;
  }
  __syncthreads();
  for (int l = t; l < L_; l += 256) {
    if (mm[l] == 1.f) {
      int i = l / Wd, j = l % Wd;
      int p2 = j * Hh + i;
      for (int k2 = -1; k2 <= 1; k2++) {
        int p2k = p2 + k2;
        if (p2k >= 0 && p2k < L_) {
          int j2 = p2k / Hh, i2 = p2k % Hh;
          ns1[i2 * Wd + j2] = 1;
        }
      }
    }
  }
  __syncthreads();
  for (int l = t; l < L_; l += 256) {
    if (ns1[l]) {
      for (int k1 = -1; k1 <= 1; k1++) {
        int l3 = l + k1;
        if (l3 >= 0 && l3 < L_) nraw[l3] = 1;
      }
    }
  }
  __syncthreads();
  int cN = 0, cH = 0;
  for (int q = 0; q < 9; q++) {
    int l = t * 9 + q;
    if (nraw[l]) cN++;
    if (mm[l] == 1.f) cH++;
  }
  __shared__ int sN[256], sH[256];
  sN[t] = cN; sH[t] = cH;
  __syncthreads();
  for (int off = 1; off < 256; off <<= 1) {
    int vN = (t >= off) ? sN[t - off] : 0;
    int vH = (t >= off) ? sH[t - off] : 0;
    __syncthreads();
    sN[t] += vN; sH[t] += vH;
    __syncthreads();
  }
  int bN = sN[t] - cN, bH = sH[t] - cH;
  for (int q = 0; q < 9; q++) {
    int l = t * 9 + q;
    if (nraw[l]) { if (bN < NEED_CAP) { nlist[bN] = l; row_l[l] = bN; } bN++; }
    if (mm[l] == 1.f) { if (bH < HOLE_CAP) { hlist[bH] = l; } bH++; }
  }
  if (t == 255) {
    meta[0] = sN[255] < NEED_CAP ? sN[255] : NEED_CAP;
    meta[1] = sH[255] < HOLE_CAP ? sH[255] : HOLE_CAP;
  }
}

// ---------------- downsample f,b by 2 ; also emit split bf16 f_ds in [pos][c] layout ----------------
__global__ __launch_bounds__(256) void gla_down(const float* __restrict__ f, const float* __restrict__ b,
                                                char* __restrict__ ws)
{
  int idx = blockIdx.x * 256 + threadIdx.x;
  if (idx >= B_ * C_ * L_) return;
  float* f_ds = (float*)(ws + OFF_FDS);
  float* b_ds = (float*)(ws + OFF_BDS);
  unsigned short* fdsh = (unsigned short*)(ws + OFF_FDSH);
  unsigned short* fdsl = (unsigned short*)(ws + OFF_FDSL);
  int pos = idx % L_;
  int x = pos % Wd, y = pos / Wd;
  int ic = idx / L_;
  int c = ic % C_, ib = ic / C_;
  size_t src = ((size_t)ic * FH + 2 * y) * FW + 2 * x;
  float fv = f[src];
  f_ds[idx] = fv;
  b_ds[idx] = b[src];
  unsigned short hi, lo;
  split2(fv, hi, lo);
  size_t o = ((size_t)ib * L_ + pos) * C_ + c;
  fdsh[o] = hi;
  fdsl[o] = lo;
}

// ---------------- per-needed-patch attention -> wn (bf16 hi/lo, tap-major k) ----------------
__global__ __launch_bounds__(128) void gla_patch(const float* __restrict__ wq, const float* __restrict__ bq,
                                                 const float* __restrict__ wk, const float* __restrict__ bk,
                                                 const float* __restrict__ wv, const float* __restrict__ bv,
                                                 const float* __restrict__ beta2p, char* __restrict__ ws)
{
  const int* meta = (const int*)(ws + OFF_META);
  int r = blockIdx.x;
  if (r >= meta[0]) return;
  int ib = blockIdx.y;
  const int* nlist = (const int*)(ws + OFF_NLIST);
  const float* m_p = (const float*)(ws + OFF_MP);
  const float* f_ds = (const float*)(ws + OFF_FDS) + (size_t)ib * C_ * L_;
  const float* b_ds = (const float*)(ws + OFF_BDS) + (size_t)ib * C_ * L_;
  unsigned short* wnh = (unsigned short*)(ws + OFF_WNH) + ((size_t)ib * NEED_CAP + r) * KC;
  unsigned short* wnl = (unsigned short*)(ws + OFF_WNL) + ((size_t)ib * NEED_CAP + r) * KC;

  __shared__ float fi[C_ * 9], wi[C_ * 9];
  __shared__ float qs[9 * D_], ks[D_ * 9], att[81], mps[9];
  __shared__ float wvs[C_ * 33];
  __shared__ float red[128];

  const int t = threadIdx.x;
  int l = nlist[r];
  int y = l / Wd, x = l % Wd;
  for (int idx = t; idx < C_ * 9; idx += 128) {
    int c = idx / 9, tap = idx % 9, dy = tap / 3, dx = tap % 3;
    int sy = y + dy - 1, sx = x + dx - 1;
    float fv = 0.f, bv2 = 0.f;
    if ((unsigned)sy < (unsigned)Hh && (unsigned)sx < (unsigned)Wd) {
      size_t o = (size_t)c * L_ + sy * Wd + sx;
      fv = f_ds[o]; bv2 = b_ds[o];
    }
    fi[idx] = fv; wi[idx] = bv2;
  }
  if (t < 9) mps[t] = m_p[l * 9 + t];
  __syncthreads();
  for (int o = t; o < 288; o += 128) {
    if (o < 144) {
      int n = o / D_, d = o % D_;
      float s = bq[d];
      for (int c = 0; c < C_; c++) s += fi[c * 9 + n] * wq[d * C_ + c];
      qs[n * D_ + d] = s;
    } else {
      int o2 = o - 144;
      int d = o2 / 9, m = o2 % 9;
      float s = bk[d];
      for (int c = 0; c < C_; c++) s += wi[c * 9 + m] * wk[d * C_ + c];
      ks[d * 9 + m] = s;
    }
  }
  __syncthreads();
  if (t < 81) {
    int n = t / 9, m = t % 9;
    float s = 0.f;
    for (int d = 0; d < D_; d++) s += qs[n * D_ + d] * ks[d * 9 + m];
    att[t] = s * mps[m];
  }
  __syncthreads();
  if (t < 9) {
    float mx = -1e30f;
    for (int m = 0; m < 9; m++) mx = fmaxf(mx, att[t * 9 + m]);
    float e[9], sm = 0.f;
    for (int m = 0; m < 9; m++) { e[m] = expf(att[t * 9 + m] - mx); sm += e[m]; }
    float inv = 1.f / sm;
    for (int m = 0; m < 9; m++) att[t * 9 + m] = e[m] * inv;
  }
  __syncthreads();
  const int c = t;
  float vn[9];
  for (int n = 0; n < 9; n++) vn[n] = bv[c];
  for (int ch = 0; ch < 4; ch++) {
    for (int idx = t; idx < C_ * 32; idx += 128) {
      int cc = idx / 32, q = idx % 32;
      wvs[cc * 33 + q] = wv[cc * C_ + ch * 32 + q];
    }
    __syncthreads();
    for (int q = 0; q < 32; q++) {
      float w = wvs[c * 33 + q];
      int cp = ch * 32 + q;
      #pragma unroll
      for (int n = 0; n < 9; n++) vn[n] += fi[cp * 9 + n] * w;
    }
    __syncthreads();
  }
  float beta2 = beta2p[0];
  float fm[9];
  #pragma unroll
  for (int m = 0; m < 9; m++) {
    float s = 0.f;
    #pragma unroll
    for (int n = 0; n < 9; n++) s += vn[n] * att[m * 9 + n];
    float mp = mps[m];
    fm[m] = beta2 * fi[c * 9 + m] * mp + (1.f - mp) * s;
  }
  float ss = 0.f;
  #pragma unroll
  for (int m = 0; m < 9; m++) ss += fm[m] * fm[m];
  red[t] = ss;
  __syncthreads();
  for (int off = 64; off > 0; off >>= 1) {
    if (t < off) red[t] += red[t + off];
    __syncthreads();
  }
  float inv = 1.f / fmaxf(sqrtf(red[0]), EPS_);
  #pragma unroll
  for (int m = 0; m < 9; m++) {       // tap-major: k = m*128 + c
    unsigned short hi, lo;
    split2(fm[m] * inv, hi, lo);
    wnh[m * C_ + c] = hi;
    wnl[m * C_ + c] = lo;
  }
}

// ---------------- corr GEMM via split-bf16 MFMA (tap-major K, b128-only staging) ----------------
__global__ __launch_bounds__(256) void gla_corr(char* __restrict__ ws)
{
  const int ib = blockIdx.z;
  const int r0 = blockIdx.x * 64, x0 = blockIdx.y * 64;
  const unsigned short* Ahg = (const unsigned short*)(ws + OFF_WNH) + (size_t)ib * NEED_CAP * KC;
  const unsigned short* Alg = (const unsigned short*)(ws + OFF_WNL) + (size_t)ib * NEED_CAP * KC;
  const unsigned short* fh = (const unsigned short*)(ws + OFF_FDSH) + (size_t)ib * L_ * C_;
  const unsigned short* fl = (const unsigned short*)(ws + OFF_FDSL) + (size_t)ib * L_ * C_;
  float* S = (float*)(ws + OFF_SRAW) + (size_t)ib * NEED_CAP * L_;

  __shared__ short Ah[64][40], Al[64][40], Bh[64][40], Bl[64][40];
  const int tid = threadIdx.x;
  const int lane = tid & 63, w = tid >> 6;
  const int wr = w >> 1, wc = w & 1;
  const int fr = lane & 15, kq = (lane >> 4) * 8;
  const int xc = tid & 63, j = tid >> 6;
  const int xg = x0 + xc;
  const int aa = xg / Wd, bb = xg % Wd;

  f32x4 acc[2][2];
  #pragma unroll
  for (int i = 0; i < 2; i++)
    #pragma unroll
    for (int jj = 0; jj < 2; jj++)
      #pragma unroll
      for (int q = 0; q < 4; q++) acc[i][jj][q] = 0.f;

  for (int tap = 0; tap < 9; tap++) {
    const int dy = tap / 3, dx = tap % 3;
    const int sy = aa + dy - 1, sx = bb + dx - 1;
    const bool valid = ((unsigned)sy < (unsigned)Hh) && ((unsigned)sx < (unsigned)Wd);
    const size_t bpos = valid ? (size_t)(sy * Wd + sx) * C_ : 0;
    for (int kc = 0; kc < 4; kc++) {
      const int k0 = tap * 128 + kc * 32;
      {
        size_t off = (size_t)(r0 + xc) * KC + k0 + j * 8;
        *(bf16x8*)&Ah[xc][j * 8] = *(const bf16x8*)&Ahg[off];
        *(bf16x8*)&Al[xc][j * 8] = *(const bf16x8*)&Alg[off];
      }
      {
        const int c0 = kc * 32 + j * 8;
        bf16x8 vh = {0,0,0,0,0,0,0,0}, vl = {0,0,0,0,0,0,0,0};
        if (valid) {
          vh = *(const bf16x8*)&fh[bpos + c0];
          vl = *(const bf16x8*)&fl[bpos + c0];
        }
        *(bf16x8*)&Bh[xc][j * 8] = vh;
        *(bf16x8*)&Bl[xc][j * 8] = vl;
      }
      __syncthreads();
      bf16x8 ah0 = *(const bf16x8*)&Ah[wr * 32 + fr][kq];
      bf16x8 ah1 = *(const bf16x8*)&Ah[wr * 32 + 16 + fr][kq];
      bf16x8 al0 = *(const bf16x8*)&Al[wr * 32 + fr][kq];
      bf16x8 al1 = *(const bf16x8*)&Al[wr * 32 + 16 + fr][kq];
      bf16x8 bh0 = *(const bf16x8*)&Bh[wc * 32 + fr][kq];
      bf16x8 bh1 = *(const bf16x8*)&Bh[wc * 32 + 16 + fr][kq];
      bf16x8 bl0 = *(const bf16x8*)&Bl[wc * 32 + fr][kq];
      bf16x8 bl1 = *(const bf16x8*)&Bl[wc * 32 + 16 + fr][kq];
      acc[0][0] = mfma16(ah0, bh0, acc[0][0]);
      acc[0][0] = mfma16(ah0, bl0, acc[0][0]);
      acc[0][0] = mfma16(al0, bh0, acc[0][0]);
      acc[0][1] = mfma16(ah0, bh1, acc[0][1]);
      acc[0][1] = mfma16(ah0, bl1, acc[0][1]);
      acc[0][1] = mfma16(al0, bh1, acc[0][1]);
      acc[1][0] = mfma16(ah1, bh0, acc[1][0]);
      acc[1][0] = mfma16(ah1, bl0, acc[1][0]);
      acc[1][0] = mfma16(al1, bh0, acc[1][0]);
      acc[1][1] = mfma16(ah1, bh1, acc[1][1]);
      acc[1][1] = mfma16(ah1, bl1, acc[1][1]);
      acc[1][1] = mfma16(al1, bh1, acc[1][1]);
      __syncthreads();
    }
  }
  #pragma unroll
  for (int mi = 0; mi < 2; mi++)
    #pragma unroll
    for (int ni = 0; ni < 2; ni++) {
      int row0 = r0 + wr * 32 + mi * 16 + (lane >> 4) * 4;
      int col = x0 + wc * 32 + ni * 16 + (lane & 15);
      #pragma unroll
      for (int q = 0; q < 4; q++)
        S[(size_t)(row0 + q) * L_ + col] = acc[mi][ni][q];
    }
}

// ---------------- fuse: two diagonal 3-taps in flattened index space ----------------
__global__ __launch_bounds__(256) void gla_fuse(char* __restrict__ ws)
{
  const int* meta = (const int*)(ws + OFF_META);
  int rh = blockIdx.y;
  if (rh >= meta[1]) return;
  int ib = blockIdx.z;
  const int* hlist = (const int*)(ws + OFF_HLIST);
  const int* row_l = (const int*)(ws + OFF_ROWL);
  const float* S = (const float*)(ws + OFF_SRAW) + (size_t)ib * NEED_CAP * L_;
  float* Sf = (float*)(ws + OFF_SF) + ((size_t)ib * HOLE_CAP + rh) * L_;
  int x = blockIdx.x * 256 + threadIdx.x;
  int l = hlist[rh];
  int i = l / Wd, j = l % Wd;
  int a = x / Wd, b = x % Wd;
  int p2 = j * Hh + i, q2 = b * Hh + a;
  float acc = 0.f;
  #pragma unroll
  for (int k2 = -1; k2 <= 1; k2++) {
    int p2k = p2 + k2, q2k = q2 + k2;
    if (p2k < 0 || p2k >= L_ || q2k < 0 || q2k >= L_) continue;
    int j2 = p2k / Hh, i2 = p2k % Hh;
    int b2 = q2k / Hh, a2 = q2k % Hh;
    int l1 = i2 * Wd + j2, x1 = a2 * Wd + b2;
    #pragma unroll
    for (int k1 = -1; k1 <= 1; k1++) {
      int l3 = l1 + k1, x3 = x1 + k1;
      if (l3 < 0 || l3 >= L_ || x3 < 0 || x3 >= L_) continue;
      int r = row_l[l3];
      if (r >= 0) acc += S[(size_t)r * L_ + x3];
    }
  }
  Sf[x] = acc;
}

// ---------------- column softmax -> split transposed P (bf16 hi/lo, [x][rh]) ----------------
__global__ __launch_bounds__(256) void gla_softmax(char* __restrict__ ws)
{
  const int* meta = (const int*)(ws + OFF_META);
  const int hc = meta[1];
  int ib = blockIdx.y;
  int xl = threadIdx.x & 63, g = threadIdx.x >> 6;
  int x = blockIdx.x * 64 + xl;
  const float* Sf = (const float*)(ws + OFF_SF) + (size_t)ib * HOLE_CAP * L_;
  unsigned short* Ph = (unsigned short*)(ws + OFF_PHT) + ((size_t)ib * L_ + x) * HOLE_CAP;
  unsigned short* Pl = (unsigned short*)(ws + OFF_PLT) + ((size_t)ib * L_ + x) * HOLE_CAP;
  __shared__ float red[4][64];
  float mx = 0.f;   // zero rows contribute max >= 0
  for (int rh = g; rh < hc; rh += 4) mx = fmaxf(mx, SCALE_ * Sf[(size_t)rh * L_ + x]);
  red[g][xl] = mx;
  __syncthreads();
  mx = fmaxf(fmaxf(red[0][xl], red[1][xl]), fmaxf(red[2][xl], red[3][xl]));
  float s = 0.f;
  for (int rh = g; rh < hc; rh += 4) s += expf(SCALE_ * Sf[(size_t)rh * L_ + x] - mx);
  __syncthreads();
  red[g][xl] = s;
  __syncthreads();
  float den = (float)(L_ - hc) * expf(-mx) + red[0][xl] + red[1][xl] + red[2][xl] + red[3][xl];
  float inv = 1.f / den;
  for (int rh = g; rh < hc; rh += 4) {
    float e = expf(SCALE_ * Sf[(size_t)rh * L_ + x] - mx) * inv;
    unsigned short hi, lo;
    split2(e, hi, lo);
    Ph[rh] = hi; Pl[rh] = lo;
  }
  for (int rh = hc + g; rh < HOLE_CAP; rh += 4) { Ph[rh] = 0; Pl[rh] = 0; }
}

// ---------------- pack raw_w (bf16 hi/lo) ----------------
__global__ __launch_bounds__(256) void gla_packRW(const float* __restrict__ b, char* __restrict__ ws, int ib)
{
  int idx = blockIdx.x * 256 + threadIdx.x;
  if (idx >= 2048 * HOLE_CAP) return;
  const int* meta = (const int*)(ws + OFF_META);
  const int* hlist = (const int*)(ws + OFF_HLIST);
  unsigned short* RWH = (unsigned short*)(ws + OFF_RWH);
  unsigned short* RWL = (unsigned short*)(ws + OFF_RWL);
  int c2 = idx / HOLE_CAP, rh = idx % HOLE_CAP;
  float v = 0.f;
  if (rh < meta[1]) {
    int l = hlist[rh];
    int yy = l / Wd, xx = l % Wd;
    int c = c2 >> 4, ty = (c2 >> 2) & 3, tx = c2 & 3;
    int sy = 2 * yy - 1 + ty, sx = 2 * xx - 1 + tx;
    if ((unsigned)sy < (unsigned)FH && (unsigned)sx < (unsigned)FW)
      v = b[((size_t)(ib * C_ + c) * FH + sy) * FW + sx];
  }
  unsigned short hi, lo;
  split2(v, hi, lo);
  RWH[idx] = hi;
  RWL[idx] = lo;
}

// ---------------- T-GEMM via split-bf16 MFMA (b128-only staging) ----------------
__global__ __launch_bounds__(256) void gla_tgemm(char* __restrict__ ws, int ib)
{
  const int* meta = (const int*)(ws + OFF_META);
  const int kend = (((meta[1] + 31) >> 5) << 5);
  const unsigned short* Ahg = (const unsigned short*)(ws + OFF_RWH);
  const unsigned short* Alg = (const unsigned short*)(ws + OFF_RWL);
  const unsigned short* Ph = (const unsigned short*)(ws + OFF_PHT) + (size_t)ib * L_ * HOLE_CAP;
  const unsigned short* Pl = (const unsigned short*)(ws + OFF_PLT) + (size_t)ib * L_ * HOLE_CAP;
  float* T = (float*)(ws + OFF_T);

  __shared__ short Ah[64][40], Al[64][40], Bh[64][40], Bl[64][40];
  const int tid = threadIdx.x;
  const int lane = tid & 63, w = tid >> 6;
  const int wr = w >> 1, wc = w & 1;
  const int fr = lane & 15, kq = (lane >> 4) * 8;
  const int m0 = blockIdx.x * 64, x0 = blockIdx.y * 64;
  const int xc = tid & 63, j = tid >> 6;

  f32x4 acc[2][2];
  #pragma unroll
  for (int i = 0; i < 2; i++)
    #pragma unroll
    for (int jj = 0; jj < 2; jj++)
      #pragma unroll
      for (int q = 0; q < 4; q++) acc[i][jj][q] = 0.f;

  for (int k0 = 0; k0 < kend; k0 += 32) {
    {
      size_t off = (size_t)(m0 + xc) * HOLE_CAP + k0 + j * 8;
      *(bf16x8*)&Ah[xc][j * 8] = *(const bf16x8*)&Ahg[off];
      *(bf16x8*)&Al[xc][j * 8] = *(const bf16x8*)&Alg[off];
    }
    {
      size_t off = (size_t)(x0 + xc) * HOLE_CAP + k0 + j * 8;
      *(bf16x8*)&Bh[xc][j * 8] = *(const bf16x8*)&Ph[off];
      *(bf16x8*)&Bl[xc][j * 8] = *(const bf16x8*)&Pl[off];
    }
    __syncthreads();
    bf16x8 ah0 = *(const bf16x8*)&Ah[wr * 32 + fr][kq];
    bf16x8 ah1 = *(const bf16x8*)&Ah[wr * 32 + 16 + fr][kq];
    bf16x8 al0 = *(const bf16x8*)&Al[wr * 32 + fr][kq];
    bf16x8 al1 = *(const bf16x8*)&Al[wr * 32 + 16 + fr][kq];
    bf16x8 bh0 = *(const bf16x8*)&Bh[wc * 32 + fr][kq];
    bf16x8 bh1 = *(const bf16x8*)&Bh[wc * 32 + 16 + fr][kq];
    bf16x8 bl0 = *(const bf16x8*)&Bl[wc * 32 + fr][kq];
    bf16x8 bl1 = *(const bf16x8*)&Bl[wc * 32 + 16 + fr][kq];
    acc[0][0] = mfma16(ah0, bh0, acc[0][0]);
    acc[0][0] = mfma16(ah0, bl0, acc[0][0]);
    acc[0][0] = mfma16(al0, bh0, acc[0][0]);
    acc[0][1] = mfma16(ah0, bh1, acc[0][1]);
    acc[0][1] = mfma16(ah0, bl1, acc[0][1]);
    acc[0][1] = mfma16(al0, bh1, acc[0][1]);
    acc[1][0] = mfma16(ah1, bh0, acc[1][0]);
    acc[1][0] = mfma16(ah1, bl0, acc[1][0]);
    acc[1][0] = mfma16(al1, bh0, acc[1][0]);
    acc[1][1] = mfma16(ah1, bh1, acc[1][1]);
    acc[1][1] = mfma16(ah1, bl1, acc[1][1]);
    acc[1][1] = mfma16(al1, bh1, acc[1][1]);
    __syncthreads();
  }
  #pragma unroll
  for (int mi = 0; mi < 2; mi++)
    #pragma unroll
    for (int ni = 0; ni < 2; ni++) {
      int row0 = m0 + wr * 32 + mi * 16 + (lane >> 4) * 4;
      int col = x0 + wc * 32 + ni * 16 + (lane & 15);
      #pragma unroll
      for (int q = 0; q < 4; q++)
        T[(size_t)(row0 + q) * L_ + col] = acc[mi][ni][q];
    }
}

// ---------------- assemble transposed-conv output from T ----------------
__global__ __launch_bounds__(256) void gla_assemble(float* __restrict__ out, const char* __restrict__ ws, int ib)
{
  int idx = blockIdx.x * 256 + threadIdx.x;
  if (idx >= C_ * FH * FW) return;
  const float* T = (const float*)(ws + OFF_T);
  int X = idx % FW;
  int Y = (idx / FW) % FH;
  int c = idx / (FH * FW);
  float s = 0.f;
  int py = (Y + 1) & 1;
  int px = (X + 1) & 1;
  #pragma unroll
  for (int sy = 0; sy < 2; sy++) {
    int ty = py + 2 * sy;
    int num = Y + 1 - ty;
    if (num < 0) continue;
    int a = num >> 1;
    if (a >= Hh) continue;
    #pragma unroll
    for (int sx = 0; sx < 2; sx++) {
      int tx = px + 2 * sx;
      int nx = X + 1 - tx;
      if (nx < 0) continue;
      int bcol = nx >> 1;
      if (bcol >= Wd) continue;
      int c2 = (c << 4) + (ty << 2) + tx;
      s += T[(size_t)c2 * L_ + a * Wd + bcol];
    }
  }
  out[((size_t)(ib * C_ + c) * FH + Y) * FW + X] = 0.25f * s;
}

extern "C" void kernel_launch(void* const* d_in, const int* in_sizes, int n_in,
                              void* d_out, int out_size, void* d_ws, size_t ws_size,
                              hipStream_t stream)
{
  (void)in_sizes; (void)n_in; (void)out_size; (void)ws_size;
  const float* f    = (const float*)d_in[0];
  const float* b    = (const float*)d_in[1];
  const float* mask = (const float*)d_in[2];
  const float* wq   = (const float*)d_in[3];
  const float* bq   = (const float*)d_in[4];
  const float* wk   = (const float*)d_in[5];
  const float* bk   = (const float*)d_in[6];
  const float* wv   = (const float*)d_in[7];
  const float* bv   = (const float*)d_in[8];
  const float* bt2  = (const float*)d_in[9];
  float* out = (float*)d_out;
  char* ws = (char*)d_ws;

  hipLaunchKernelGGL(gla_prep, dim3(1), dim3(256), 0, stream, mask, ws);
  hipLaunchKernelGGL(gla_down, dim3((B_ * C_ * L_ + 255) / 256), dim3(256), 0, stream, f, b, ws);
  hipLaunchKernelGGL(gla_patch, dim3(NEED_CAP, B_), dim3(128), 0, stream,
                     wq, bq, wk, bk, wv, bv, bt2, ws);
  hipLaunchKernelGGL(gla_corr, dim3(NEED_CAP / 64, L_ / 64, B_), dim3(256), 0, stream, ws);
  hipLaunchKernelGGL(gla_fuse, dim3(L_ / 256, HOLE_CAP, B_), dim3(256), 0, stream, ws);
  hipLaunchKernelGGL(gla_softmax, dim3(L_ / 64, B_), dim3(256), 0, stream, ws);
  for (int ib = 0; ib < B_; ib++) {
    hipLaunchKernelGGL(gla_packRW, dim3((2048 * HOLE_CAP + 255) / 256), dim3(256), 0, stream, b, ws, ib);
    hipLaunchKernelGGL(gla_tgemm, dim3(2048 / 64, L_ / 64), dim3(256), 0, stream, ws, ib);
    hipLaunchKernelGGL(gla_assemble, dim3((C_ * FH * FW + 255) / 256), dim3(256), 0, stream, out, ws, ib);
  }
}

// Round 4
// 444.619 us; speedup vs baseline: 1.2421x; 1.2421x over previous
//
#include <hip/hip_runtime.h>
#include <math.h>

// GlobalLocalAttention — mask-sparse pipeline, GEMMs via bf16x2-split MFMA.
// R4: x-fastest dispatch + XCD swizzle (A-panel L2 reuse), reg-prefetch pipeline,
//     BN=128 tiles; LDS-transpose coalescing for split/softmax writes.

constexpr int B_ = 4, C_ = 128, D_ = 16;
constexpr int FH = 96, FW = 96;
constexpr int Hh = 48, Wd = 48;
constexpr int L_ = Hh * Wd;           // 2304
constexpr int NEED_CAP = 384, HOLE_CAP = 320;
constexpr int KC = C_ * 9;            // 1152
constexpr float SCALE_ = 10.0f;
constexpr float EPS_ = 1e-4f;

typedef __attribute__((ext_vector_type(8))) short bf16x8;
typedef __attribute__((ext_vector_type(4))) float f32x4;
typedef __attribute__((ext_vector_type(4))) short s16x4;
typedef __attribute__((ext_vector_type(2))) unsigned short u16x2;

static __device__ __forceinline__ f32x4 mfma16(bf16x8 a, bf16x8 b, f32x4 c) {
  return __builtin_amdgcn_mfma_f32_16x16x32_bf16(a, b, c, 0, 0, 0);
}
static __device__ __forceinline__ unsigned short bf16_rne(float f) {
  unsigned u = __builtin_bit_cast(unsigned, f);
  unsigned r = (u + 0x7FFFu + ((u >> 16) & 1u)) >> 16;
  return (unsigned short)r;
}
static __device__ __forceinline__ float bf16f(unsigned short h) {
  unsigned u = ((unsigned)h) << 16;
  return __builtin_bit_cast(float, u);
}
static __device__ __forceinline__ void split2(float v, unsigned short& hi, unsigned short& lo) {
  hi = bf16_rne(v);
  lo = bf16_rne(v - bf16f(hi));
}

constexpr size_t A256(size_t v) { return (v + 255) & ~size_t(255); }
constexpr size_t OFF_META  = 0;
constexpr size_t OFF_MDS   = A256(OFF_META + 64 * 4);
constexpr size_t OFF_MP    = A256(OFF_MDS + (size_t)L_ * 4);
constexpr size_t OFF_MM    = A256(OFF_MP + (size_t)L_ * 9 * 4);
constexpr size_t OFF_ROWL  = A256(OFF_MM + (size_t)L_ * 4);
constexpr size_t OFF_NLIST = A256(OFF_ROWL + (size_t)L_ * 4);
constexpr size_t OFF_HLIST = A256(OFF_NLIST + (size_t)NEED_CAP * 4);
constexpr size_t OFF_NS1   = A256(OFF_HLIST + (size_t)HOLE_CAP * 4);
constexpr size_t OFF_NRAW  = A256(OFF_NS1 + (size_t)L_ * 4);
constexpr size_t OFF_FDS   = A256(OFF_NRAW + (size_t)L_ * 4);                    // fp32 [B][C][48][48]
constexpr size_t OFF_BDS   = A256(OFF_FDS + (size_t)B_ * C_ * L_ * 4);
constexpr size_t OFF_FDSH  = A256(OFF_BDS + (size_t)B_ * C_ * L_ * 4);           // bf16 [B][pos][c]
constexpr size_t OFF_FDSL  = A256(OFF_FDSH + (size_t)B_ * L_ * C_ * 2);
constexpr size_t OFF_WNH   = A256(OFF_FDSL + (size_t)B_ * L_ * C_ * 2);          // bf16 [B][384][1152] tap-major k
constexpr size_t OFF_WNL   = A256(OFF_WNH + (size_t)B_ * NEED_CAP * KC * 2);
constexpr size_t OFF_SRAW  = A256(OFF_WNL + (size_t)B_ * NEED_CAP * KC * 2);     // fp32 [B][384][L]
constexpr size_t OFF_SF    = A256(OFF_SRAW + (size_t)B_ * NEED_CAP * L_ * 4);    // fp32 [B][320][L]
constexpr size_t OFF_PHT   = A256(OFF_SF + (size_t)B_ * HOLE_CAP * L_ * 4);      // bf16 [B][x][rh] transposed
constexpr size_t OFF_PLT   = A256(OFF_PHT + (size_t)B_ * L_ * HOLE_CAP * 2);
constexpr size_t OFF_RWH   = A256(OFF_PLT + (size_t)B_ * L_ * HOLE_CAP * 2);     // bf16 [2048][320]
constexpr size_t OFF_RWL   = A256(OFF_RWH + (size_t)2048 * HOLE_CAP * 2);
constexpr size_t OFF_T     = A256(OFF_RWL + (size_t)2048 * HOLE_CAP * 2);        // fp32 [2048][L]
// total ~80.6 MB

// ---------------- mask prep + compaction ----------------
__global__ __launch_bounds__(256) void gla_prep(const float* __restrict__ mask, char* __restrict__ ws)
{
  float* m_ds = (float*)(ws + OFF_MDS);
  float* m_p  = (float*)(ws + OFF_MP);
  float* mm   = (float*)(ws + OFF_MM);
  int* row_l  = (int*)(ws + OFF_ROWL);
  int* nlist  = (int*)(ws + OFF_NLIST);
  int* hlist  = (int*)(ws + OFF_HLIST);
  int* ns1    = (int*)(ws + OFF_NS1);
  int* nraw   = (int*)(ws + OFF_NRAW);
  int* meta   = (int*)(ws + OFF_META);
  const int t = threadIdx.x;

  for (int l = t; l < L_; l += 256) {
    int y = l / Wd, x = l % Wd;
    m_ds[l] = mask[(size_t)(8 * y) * 384 + 8 * x];
  }
  __syncthreads();
  for (int l = t; l < L_; l += 256) {
    int y = l / Wd, x = l % Wd;
    bool all0 = true;
    for (int dy = 0; dy < 3; dy++)
      for (int dx = 0; dx < 3; dx++) {
        int sy = y + dy - 1, sx = x + dx - 1;
        float v = ((unsigned)sy < (unsigned)Hh && (unsigned)sx < (unsigned)Wd) ? m_ds[sy * Wd + sx] : 0.f;
        m_p[l * 9 + dy * 3 + dx] = v;
        if (v != 0.f) all0 = false;
      }
    mm[l] = all0 ? 1.f : 0.f;
    ns1[l] = 0; nraw[l] = 0; row_l[l] = -1;
  }
  __syncthreads();
  for (int l = t; l < L_; l += 256) {
    if (mm[l] == 1.f) {
      int i = l / Wd, j = l % Wd;
      int p2 = j * Hh + i;
      for (int k2 = -1; k2 <= 1; k2++) {
        int p2k = p2 + k2;
        if (p2k >= 0 && p2k < L_) {
          int j2 = p2k / Hh, i2 = p2k % Hh;
          ns1[i2 * Wd + j2] = 1;
        }
      }
    }
  }
  __syncthreads();
  for (int l = t; l < L_; l += 256) {
    if (ns1[l]) {
      for (int k1 = -1; k1 <= 1; k1++) {
        int l3 = l + k1;
        if (l3 >= 0 && l3 < L_) nraw[l3] = 1;
      }
    }
  }
  __syncthreads();
  int cN = 0, cH = 0;
  for (int q = 0; q < 9; q++) {
    int l = t * 9 + q;
    if (nraw[l]) cN++;
    if (mm[l] == 1.f) cH++;
  }
  __shared__ int sN[256], sH[256];
  sN[t] = cN; sH[t] = cH;
  __syncthreads();
  for (int off = 1; off < 256; off <<= 1) {
    int vN = (t >= off) ? sN[t - off] : 0;
    int vH = (t >= off) ? sH[t - off] : 0;
    __syncthreads();
    sN[t] += vN; sH[t] += vH;
    __syncthreads();
  }
  int bN = sN[t] - cN, bH = sH[t] - cH;
  for (int q = 0; q < 9; q++) {
    int l = t * 9 + q;
    if (nraw[l]) { if (bN < NEED_CAP) { nlist[bN] = l; row_l[l] = bN; } bN++; }
    if (mm[l] == 1.f) { if (bH < HOLE_CAP) { hlist[bH] = l; } bH++; }
  }
  if (t == 255) {
    meta[0] = sN[255] < NEED_CAP ? sN[255] : NEED_CAP;
    meta[1] = sH[255] < HOLE_CAP ? sH[255] : HOLE_CAP;
  }
}

// ---------------- downsample f,b by 2 (coalesced c-major fp32) ----------------
__global__ __launch_bounds__(256) void gla_down(const float* __restrict__ f, const float* __restrict__ b,
                                                char* __restrict__ ws)
{
  int idx = blockIdx.x * 256 + threadIdx.x;
  if (idx >= B_ * C_ * L_) return;
  float* f_ds = (float*)(ws + OFF_FDS);
  float* b_ds = (float*)(ws + OFF_BDS);
  int x = idx % Wd;
  int y = (idx / Wd) % Hh;
  int ic = idx / L_;
  size_t src = ((size_t)ic * FH + 2 * y) * FW + 2 * x;
  f_ds[idx] = f[src];
  b_ds[idx] = b[src];
}

// ---------------- transpose-split f_ds -> fdsh/fdsl [pos][c] (LDS transpose, coalesced) ----------------
__global__ __launch_bounds__(256) void gla_split(char* __restrict__ ws)
{
  const int y = blockIdx.x, ib = blockIdx.y;
  const float* f_ds = (const float*)(ws + OFF_FDS) + (size_t)ib * C_ * L_;
  unsigned short* fdsh = (unsigned short*)(ws + OFF_FDSH);
  unsigned short* fdsl = (unsigned short*)(ws + OFF_FDSL);
  __shared__ float tile[48][130];
  const int t = threadIdx.x;
  for (int idx = t; idx < 48 * C_; idx += 256) {
    int x = idx % 48, c = idx / 48;
    tile[x][c] = f_ds[(size_t)c * L_ + y * Wd + x];
  }
  __syncthreads();
  for (int i = 0; i < 12; i++) {
    int p = t + i * 256;              // 0..3071
    int c2 = p & 63, x = p >> 6;      // pair idx, row
    float v0 = tile[x][c2 * 2], v1 = tile[x][c2 * 2 + 1];
    unsigned short h0, l0, h1, l1;
    split2(v0, h0, l0);
    split2(v1, h1, l1);
    size_t o = ((size_t)ib * L_ + (size_t)y * Wd + x) * C_ + c2 * 2;
    *(u16x2*)&fdsh[o] = u16x2{h0, h1};
    *(u16x2*)&fdsl[o] = u16x2{l0, l1};
  }
}

// ---------------- per-needed-patch attention -> wn (bf16 hi/lo, tap-major k) ----------------
__global__ __launch_bounds__(128) void gla_patch(const float* __restrict__ wq, const float* __restrict__ bq,
                                                 const float* __restrict__ wk, const float* __restrict__ bk,
                                                 const float* __restrict__ wv, const float* __restrict__ bv,
                                                 const float* __restrict__ beta2p, char* __restrict__ ws)
{
  const int* meta = (const int*)(ws + OFF_META);
  int r = blockIdx.x;
  if (r >= meta[0]) return;
  int ib = blockIdx.y;
  const int* nlist = (const int*)(ws + OFF_NLIST);
  const float* m_p = (const float*)(ws + OFF_MP);
  const float* f_ds = (const float*)(ws + OFF_FDS) + (size_t)ib * C_ * L_;
  const float* b_ds = (const float*)(ws + OFF_BDS) + (size_t)ib * C_ * L_;
  unsigned short* wnh = (unsigned short*)(ws + OFF_WNH) + ((size_t)ib * NEED_CAP + r) * KC;
  unsigned short* wnl = (unsigned short*)(ws + OFF_WNL) + ((size_t)ib * NEED_CAP + r) * KC;

  __shared__ float fi[C_ * 9], wi[C_ * 9];
  __shared__ float qs[9 * D_], ks[D_ * 9], att[81], mps[9];
  __shared__ float wvs[C_ * 33];
  __shared__ float red[128];

  const int t = threadIdx.x;
  int l = nlist[r];
  int y = l / Wd, x = l % Wd;
  for (int idx = t; idx < C_ * 9; idx += 128) {
    int c = idx / 9, tap = idx % 9, dy = tap / 3, dx = tap % 3;
    int sy = y + dy - 1, sx = x + dx - 1;
    float fv = 0.f, bv2 = 0.f;
    if ((unsigned)sy < (unsigned)Hh && (unsigned)sx < (unsigned)Wd) {
      size_t o = (size_t)c * L_ + sy * Wd + sx;
      fv = f_ds[o]; bv2 = b_ds[o];
    }
    fi[idx] = fv; wi[idx] = bv2;
  }
  if (t < 9) mps[t] = m_p[l * 9 + t];
  __syncthreads();
  for (int o = t; o < 288; o += 128) {
    if (o < 144) {
      int n = o / D_, d = o % D_;
      float s = bq[d];
      for (int c = 0; c < C_; c++) s += fi[c * 9 + n] * wq[d * C_ + c];
      qs[n * D_ + d] = s;
    } else {
      int o2 = o - 144;
      int d = o2 / 9, m = o2 % 9;
      float s = bk[d];
      for (int c = 0; c < C_; c++) s += wi[c * 9 + m] * wk[d * C_ + c];
      ks[d * 9 + m] = s;
    }
  }
  __syncthreads();
  if (t < 81) {
    int n = t / 9, m = t % 9;
    float s = 0.f;
    for (int d = 0; d < D_; d++) s += qs[n * D_ + d] * ks[d * 9 + m];
    att[t] = s * mps[m];
  }
  __syncthreads();
  if (t < 9) {
    float mx = -1e30f;
    for (int m = 0; m < 9; m++) mx = fmaxf(mx, att[t * 9 + m]);
    float e[9], sm = 0.f;
    for (int m = 0; m < 9; m++) { e[m] = expf(att[t * 9 + m] - mx); sm += e[m]; }
    float inv = 1.f / sm;
    for (int m = 0; m < 9; m++) att[t * 9 + m] = e[m] * inv;
  }
  __syncthreads();
  const int c = t;
  float vn[9];
  for (int n = 0; n < 9; n++) vn[n] = bv[c];
  for (int ch = 0; ch < 4; ch++) {
    for (int idx = t; idx < C_ * 32; idx += 128) {
      int cc = idx / 32, q = idx % 32;
      wvs[cc * 33 + q] = wv[cc * C_ + ch * 32 + q];
    }
    __syncthreads();
    for (int q = 0; q < 32; q++) {
      float w = wvs[c * 33 + q];
      int cp = ch * 32 + q;
      #pragma unroll
      for (int n = 0; n < 9; n++) vn[n] += fi[cp * 9 + n] * w;
    }
    __syncthreads();
  }
  float beta2 = beta2p[0];
  float fm[9];
  #pragma unroll
  for (int m = 0; m < 9; m++) {
    float s = 0.f;
    #pragma unroll
    for (int n = 0; n < 9; n++) s += vn[n] * att[m * 9 + n];
    float mp = mps[m];
    fm[m] = beta2 * fi[c * 9 + m] * mp + (1.f - mp) * s;
  }
  float ss = 0.f;
  #pragma unroll
  for (int m = 0; m < 9; m++) ss += fm[m] * fm[m];
  red[t] = ss;
  __syncthreads();
  for (int off = 64; off > 0; off >>= 1) {
    if (t < off) red[t] += red[t + off];
    __syncthreads();
  }
  float inv = 1.f / fmaxf(sqrtf(red[0]), EPS_);
  #pragma unroll
  for (int m = 0; m < 9; m++) {       // tap-major: k = m*128 + c
    unsigned short hi, lo;
    split2(fm[m] * inv, hi, lo);
    wnh[m * C_ + c] = hi;
    wnl[m * C_ + c] = lo;
  }
}

// ---------------- corr GEMM: BM=64 BN=128, reg-prefetch, XCD swizzle ----------------
__global__ __launch_bounds__(256) void gla_corr(char* __restrict__ ws)
{
  // 432 blocks: x-tile fastest; bijective chunked XCD swizzle (432 % 8 == 0)
  int orig = blockIdx.x;
  int wg = (orig & 7) * 54 + (orig >> 3);
  int xt = wg % 18;
  int rt = (wg / 18) % 6;
  int ib = wg / 108;
  const int r0 = rt * 64, x0 = xt * 128;

  const unsigned short* Ahg = (const unsigned short*)(ws + OFF_WNH) + (size_t)ib * NEED_CAP * KC;
  const unsigned short* Alg = (const unsigned short*)(ws + OFF_WNL) + (size_t)ib * NEED_CAP * KC;
  const unsigned short* fh = (const unsigned short*)(ws + OFF_FDSH) + (size_t)ib * L_ * C_;
  const unsigned short* fl = (const unsigned short*)(ws + OFF_FDSL) + (size_t)ib * L_ * C_;
  float* S = (float*)(ws + OFF_SRAW) + (size_t)ib * NEED_CAP * L_;

  __shared__ short Ah[64][40], Al[64][40], Bh[128][40], Bl[128][40];
  const int tid = threadIdx.x;
  const int lane = tid & 63, w = tid >> 6;
  const int fr = lane & 15, kq = (lane >> 4) * 8;
  const int arow = tid & 63, aj = tid >> 6;      // A staging: 1x bf16x8 per array
  const int bcol = tid & 127, bj = tid >> 7;     // B staging: 2x bf16x8 per array
  const int xg = x0 + bcol;
  const int aa = xg / Wd, bb = xg % Wd;

  f32x4 acc[4][2];
  #pragma unroll
  for (int mi = 0; mi < 4; mi++)
    #pragma unroll
    for (int ni = 0; ni < 2; ni++)
      #pragma unroll
      for (int q = 0; q < 4; q++) acc[mi][ni][q] = 0.f;

  const bf16x8 zz = {0, 0, 0, 0, 0, 0, 0, 0};
  bf16x8 rah, ral, rbh0, rbh1, rbl0, rbl1;

  auto load_step = [&](int s) {
    int tap = s >> 2, kc = s & 3;
    size_t aoff = (size_t)(r0 + arow) * KC + tap * 128 + kc * 32 + aj * 8;
    rah = *(const bf16x8*)&Ahg[aoff];
    ral = *(const bf16x8*)&Alg[aoff];
    int dyv = tap / 3, dxv = tap - 3 * dyv;
    int sy = aa + dyv - 1, sx = bb + dxv - 1;
    if (((unsigned)sy < (unsigned)Hh) & ((unsigned)sx < (unsigned)Wd)) {
      size_t bpos = (size_t)(sy * Wd + sx) * C_ + kc * 32 + bj * 16;
      rbh0 = *(const bf16x8*)&fh[bpos];
      rbh1 = *(const bf16x8*)&fh[bpos + 8];
      rbl0 = *(const bf16x8*)&fl[bpos];
      rbl1 = *(const bf16x8*)&fl[bpos + 8];
    } else {
      rbh0 = zz; rbh1 = zz; rbl0 = zz; rbl1 = zz;
    }
  };

  load_step(0);
  for (int s = 0; s < 36; s++) {
    __syncthreads();
    *(bf16x8*)&Ah[arow][aj * 8] = rah;
    *(bf16x8*)&Al[arow][aj * 8] = ral;
    *(bf16x8*)&Bh[bcol][bj * 16] = rbh0;
    *(bf16x8*)&Bh[bcol][bj * 16 + 8] = rbh1;
    *(bf16x8*)&Bl[bcol][bj * 16] = rbl0;
    *(bf16x8*)&Bl[bcol][bj * 16 + 8] = rbl1;
    __syncthreads();
    if (s < 35) load_step(s + 1);
    bf16x8 a_h[4], a_l[4], b_h[2], b_l[2];
    #pragma unroll
    for (int mi = 0; mi < 4; mi++) {
      a_h[mi] = *(const bf16x8*)&Ah[mi * 16 + fr][kq];
      a_l[mi] = *(const bf16x8*)&Al[mi * 16 + fr][kq];
    }
    #pragma unroll
    for (int ni = 0; ni < 2; ni++) {
      b_h[ni] = *(const bf16x8*)&Bh[w * 32 + ni * 16 + fr][kq];
      b_l[ni] = *(const bf16x8*)&Bl[w * 32 + ni * 16 + fr][kq];
    }
    #pragma unroll
    for (int mi = 0; mi < 4; mi++)
      #pragma unroll
      for (int ni = 0; ni < 2; ni++) {
        acc[mi][ni] = mfma16(a_h[mi], b_h[ni], acc[mi][ni]);
        acc[mi][ni] = mfma16(a_h[mi], b_l[ni], acc[mi][ni]);
        acc[mi][ni] = mfma16(a_l[mi], b_h[ni], acc[mi][ni]);
      }
  }
  #pragma unroll
  for (int mi = 0; mi < 4; mi++)
    #pragma unroll
    for (int ni = 0; ni < 2; ni++) {
      int row0 = r0 + mi * 16 + (lane >> 4) * 4;
      int col = x0 + w * 32 + ni * 16 + fr;
      #pragma unroll
      for (int q = 0; q < 4; q++)
        S[(size_t)(row0 + q) * L_ + col] = acc[mi][ni][q];
    }
}

// ---------------- fuse: two diagonal 3-taps in flattened index space ----------------
__global__ __launch_bounds__(256) void gla_fuse(char* __restrict__ ws)
{
  const int* meta = (const int*)(ws + OFF_META);
  int rh = blockIdx.y;
  if (rh >= meta[1]) return;
  int ib = blockIdx.z;
  const int* hlist = (const int*)(ws + OFF_HLIST);
  const int* row_l = (const int*)(ws + OFF_ROWL);
  const float* S = (const float*)(ws + OFF_SRAW) + (size_t)ib * NEED_CAP * L_;
  float* Sf = (float*)(ws + OFF_SF) + ((size_t)ib * HOLE_CAP + rh) * L_;
  int x = blockIdx.x * 256 + threadIdx.x;
  int l = hlist[rh];
  int i = l / Wd, j = l % Wd;
  int a = x / Wd, b = x % Wd;
  int p2 = j * Hh + i, q2 = b * Hh + a;
  float acc = 0.f;
  #pragma unroll
  for (int k2 = -1; k2 <= 1; k2++) {
    int p2k = p2 + k2, q2k = q2 + k2;
    if (p2k < 0 || p2k >= L_ || q2k < 0 || q2k >= L_) continue;
    int j2 = p2k / Hh, i2 = p2k % Hh;
    int b2 = q2k / Hh, a2 = q2k % Hh;
    int l1 = i2 * Wd + j2, x1 = a2 * Wd + b2;
    #pragma unroll
    for (int k1 = -1; k1 <= 1; k1++) {
      int l3 = l1 + k1, x3 = x1 + k1;
      if (l3 < 0 || l3 >= L_ || x3 < 0 || x3 >= L_) continue;
      int r = row_l[l3];
      if (r >= 0) acc += S[(size_t)r * L_ + x3];
    }
  }
  Sf[x] = acc;
}

// ---------------- column softmax -> split transposed P, LDS-transposed coalesced writes ----------------
__global__ __launch_bounds__(256) void gla_softmax(char* __restrict__ ws)
{
  const int* meta = (const int*)(ws + OFF_META);
  const int hc = meta[1];
  const int ib = blockIdx.y;
  const int t = threadIdx.x;
  const int xl = t & 63, g = t >> 6;
  const int x0 = blockIdx.x * 64;
  const float* Sf = (const float*)(ws + OFF_SF) + (size_t)ib * HOLE_CAP * L_;
  unsigned short* Ph = (unsigned short*)(ws + OFF_PHT) + (size_t)ib * L_ * HOLE_CAP;
  unsigned short* Pl = (unsigned short*)(ws + OFF_PLT) + (size_t)ib * L_ * HOLE_CAP;
  __shared__ float red[4][64];
  __shared__ float smx[64], sinv[64];
  __shared__ short Th[64][72], Tl[64][72];
  const int x = x0 + xl;
  float mx = 0.f;   // zero rows contribute max >= 0
  for (int rh = g; rh < hc; rh += 4) mx = fmaxf(mx, SCALE_ * Sf[(size_t)rh * L_ + x]);
  red[g][xl] = mx;
  __syncthreads();
  mx = fmaxf(fmaxf(red[0][xl], red[1][xl]), fmaxf(red[2][xl], red[3][xl]));
  __syncthreads();
  float s = 0.f;
  for (int rh = g; rh < hc; rh += 4) s += expf(SCALE_ * Sf[(size_t)rh * L_ + x] - mx);
  red[g][xl] = s;
  __syncthreads();
  float den = (float)(L_ - hc) * expf(-mx) + red[0][xl] + red[1][xl] + red[2][xl] + red[3][xl];
  if (g == 0) { smx[xl] = mx; sinv[xl] = 1.f / den; }
  __syncthreads();
  for (int rh0 = 0; rh0 < HOLE_CAP; rh0 += 64) {
    for (int i = 0; i < 16; i++) {
      int idx = t + i * 256;
      int xl2 = idx & 63, rr = idx >> 6;
      int rh = rh0 + rr;
      float e = 0.f;
      if (rh < hc) e = expf(SCALE_ * Sf[(size_t)rh * L_ + x0 + xl2] - smx[xl2]) * sinv[xl2];
      unsigned short hi, lo;
      split2(e, hi, lo);
      Th[xl2][rr] = (short)hi;
      Tl[xl2][rr] = (short)lo;
    }
    __syncthreads();
    for (int i = 0; i < 4; i++) {
      int q = t + i * 256;
      int rq = q & 15, xl2 = q >> 4;
      size_t dst = (size_t)(x0 + xl2) * HOLE_CAP + rh0 + rq * 4;
      *(s16x4*)&Ph[dst] = *(const s16x4*)&Th[xl2][rq * 4];
      *(s16x4*)&Pl[dst] = *(const s16x4*)&Tl[xl2][rq * 4];
    }
    __syncthreads();
  }
}

// ---------------- pack raw_w (bf16 hi/lo) ----------------
__global__ __launch_bounds__(256) void gla_packRW(const float* __restrict__ b, char* __restrict__ ws, int ib)
{
  int idx = blockIdx.x * 256 + threadIdx.x;
  if (idx >= 2048 * HOLE_CAP) return;
  const int* meta = (const int*)(ws + OFF_META);
  const int* hlist = (const int*)(ws + OFF_HLIST);
  unsigned short* RWH = (unsigned short*)(ws + OFF_RWH);
  unsigned short* RWL = (unsigned short*)(ws + OFF_RWL);
  int c2 = idx / HOLE_CAP, rh = idx % HOLE_CAP;
  float v = 0.f;
  if (rh < meta[1]) {
    int l = hlist[rh];
    int yy = l / Wd, xx = l % Wd;
    int c = c2 >> 4, ty = (c2 >> 2) & 3, tx = c2 & 3;
    int sy = 2 * yy - 1 + ty, sx = 2 * xx - 1 + tx;
    if ((unsigned)sy < (unsigned)FH && (unsigned)sx < (unsigned)FW)
      v = b[((size_t)(ib * C_ + c) * FH + sy) * FW + sx];
  }
  unsigned short hi, lo;
  split2(v, hi, lo);
  RWH[idx] = hi;
  RWL[idx] = lo;
}

// ---------------- T-GEMM: BM=64 BN=128, reg-prefetch, XCD swizzle ----------------
__global__ __launch_bounds__(256) void gla_tgemm(char* __restrict__ ws, int ib)
{
  const int* meta = (const int*)(ws + OFF_META);
  const int steps = (meta[1] + 31) >> 5;
  // 576 blocks: x-tile fastest; swizzle (576 % 8 == 0 -> q=72)
  int orig = blockIdx.x;
  int wg = (orig & 7) * 72 + (orig >> 3);
  int xt = wg % 18;
  int mt = wg / 18;
  const int m0 = mt * 64, x0 = xt * 128;

  const unsigned short* Ahg = (const unsigned short*)(ws + OFF_RWH);
  const unsigned short* Alg = (const unsigned short*)(ws + OFF_RWL);
  const unsigned short* Ph = (const unsigned short*)(ws + OFF_PHT) + (size_t)ib * L_ * HOLE_CAP;
  const unsigned short* Pl = (const unsigned short*)(ws + OFF_PLT) + (size_t)ib * L_ * HOLE_CAP;
  float* T = (float*)(ws + OFF_T);

  __shared__ short Ah[64][40], Al[64][40], Bh[128][40], Bl[128][40];
  const int tid = threadIdx.x;
  const int lane = tid & 63, w = tid >> 6;
  const int fr = lane & 15, kq = (lane >> 4) * 8;
  const int arow = tid & 63, aj = tid >> 6;
  const int bcol = tid & 127, bj = tid >> 7;

  f32x4 acc[4][2];
  #pragma unroll
  for (int mi = 0; mi < 4; mi++)
    #pragma unroll
    for (int ni = 0; ni < 2; ni++)
      #pragma unroll
      for (int q = 0; q < 4; q++) acc[mi][ni][q] = 0.f;

  bf16x8 rah, ral, rbh0, rbh1, rbl0, rbl1;
  auto load_step = [&](int s) {
    int k0 = s * 32;
    size_t aoff = (size_t)(m0 + arow) * HOLE_CAP + k0 + aj * 8;
    rah = *(const bf16x8*)&Ahg[aoff];
    ral = *(const bf16x8*)&Alg[aoff];
    size_t boff = (size_t)(x0 + bcol) * HOLE_CAP + k0 + bj * 16;
    rbh0 = *(const bf16x8*)&Ph[boff];
    rbh1 = *(const bf16x8*)&Ph[boff + 8];
    rbl0 = *(const bf16x8*)&Pl[boff];
    rbl1 = *(const bf16x8*)&Pl[boff + 8];
  };

  load_step(0);
  for (int s = 0; s < steps; s++) {
    __syncthreads();
    *(bf16x8*)&Ah[arow][aj * 8] = rah;
    *(bf16x8*)&Al[arow][aj * 8] = ral;
    *(bf16x8*)&Bh[bcol][bj * 16] = rbh0;
    *(bf16x8*)&Bh[bcol][bj * 16 + 8] = rbh1;
    *(bf16x8*)&Bl[bcol][bj * 16] = rbl0;
    *(bf16x8*)&Bl[bcol][bj * 16 + 8] = rbl1;
    __syncthreads();
    if (s + 1 < steps) load_step(s + 1);
    bf16x8 a_h[4], a_l[4], b_h[2], b_l[2];
    #pragma unroll
    for (int mi = 0; mi < 4; mi++) {
      a_h[mi] = *(const bf16x8*)&Ah[mi * 16 + fr][kq];
      a_l[mi] = *(const bf16x8*)&Al[mi * 16 + fr][kq];
    }
    #pragma unroll
    for (int ni = 0; ni < 2; ni++) {
      b_h[ni] = *(const bf16x8*)&Bh[w * 32 + ni * 16 + fr][kq];
      b_l[ni] = *(const bf16x8*)&Bl[w * 32 + ni * 16 + fr][kq];
    }
    #pragma unroll
    for (int mi = 0; mi < 4; mi++)
      #pragma unroll
      for (int ni = 0; ni < 2; ni++) {
        acc[mi][ni] = mfma16(a_h[mi], b_h[ni], acc[mi][ni]);
        acc[mi][ni] = mfma16(a_h[mi], b_l[ni], acc[mi][ni]);
        acc[mi][ni] = mfma16(a_l[mi], b_h[ni], acc[mi][ni]);
      }
  }
  #pragma unroll
  for (int mi = 0; mi < 4; mi++)
    #pragma unroll
    for (int ni = 0; ni < 2; ni++) {
      int row0 = m0 + mi * 16 + (lane >> 4) * 4;
      int col = x0 + w * 32 + ni * 16 + fr;
      #pragma unroll
      for (int q = 0; q < 4; q++)
        T[(size_t)(row0 + q) * L_ + col] = acc[mi][ni][q];
    }
}

// ---------------- assemble transposed-conv output from T ----------------
__global__ __launch_bounds__(256) void gla_assemble(float* __restrict__ out, const char* __restrict__ ws, int ib)
{
  int idx = blockIdx.x * 256 + threadIdx.x;
  if (idx >= C_ * FH * FW) return;
  const float* T = (const float*)(ws + OFF_T);
  int X = idx % FW;
  int Y = (idx / FW) % FH;
  int c = idx / (FH * FW);
  float s = 0.f;
  int py = (Y + 1) & 1;
  int px = (X + 1) & 1;
  #pragma unroll
  for (int sy = 0; sy < 2; sy++) {
    int ty = py + 2 * sy;
    int num = Y + 1 - ty;
    if (num < 0) continue;
    int a = num >> 1;
    if (a >= Hh) continue;
    #pragma unroll
    for (int sx = 0; sx < 2; sx++) {
      int tx = px + 2 * sx;
      int nx = X + 1 - tx;
      if (nx < 0) continue;
      int bcol = nx >> 1;
      if (bcol >= Wd) continue;
      int c2 = (c << 4) + (ty << 2) + tx;
      s += T[(size_t)c2 * L_ + a * Wd + bcol];
    }
  }
  out[((size_t)(ib * C_ + c) * FH + Y) * FW + X] = 0.25f * s;
}

extern "C" void kernel_launch(void* const* d_in, const int* in_sizes, int n_in,
                              void* d_out, int out_size, void* d_ws, size_t ws_size,
                              hipStream_t stream)
{
  (void)in_sizes; (void)n_in; (void)out_size; (void)ws_size;
  const float* f    = (const float*)d_in[0];
  const float* b    = (const float*)d_in[1];
  const float* mask = (const float*)d_in[2];
  const float* wq   = (const float*)d_in[3];
  const float* bq   = (const float*)d_in[4];
  const float* wk   = (const float*)d_in[5];
  const float* bk   = (const float*)d_in[6];
  const float* wv   = (const float*)d_in[7];
  const float* bv   = (const float*)d_in[8];
  const float* bt2  = (const float*)d_in[9];
  float* out = (float*)d_out;
  char* ws = (char*)d_ws;

  hipLaunchKernelGGL(gla_prep, dim3(1), dim3(256), 0, stream, mask, ws);
  hipLaunchKernelGGL(gla_down, dim3((B_ * C_ * L_ + 255) / 256), dim3(256), 0, stream, f, b, ws);
  hipLaunchKernelGGL(gla_split, dim3(Hh, B_), dim3(256), 0, stream, ws);
  hipLaunchKernelGGL(gla_patch, dim3(NEED_CAP, B_), dim3(128), 0, stream,
                     wq, bq, wk, bk, wv, bv, bt2, ws);
  hipLaunchKernelGGL(gla_corr, dim3(432), dim3(256), 0, stream, ws);
  hipLaunchKernelGGL(gla_fuse, dim3(L_ / 256, HOLE_CAP, B_), dim3(256), 0, stream, ws);
  hipLaunchKernelGGL(gla_softmax, dim3(L_ / 64, B_), dim3(256), 0, stream, ws);
  for (int ib = 0; ib < B_; ib++) {
    hipLaunchKernelGGL(gla_packRW, dim3((2048 * HOLE_CAP + 255) / 256), dim3(256), 0, stream, b, ws, ib);
    hipLaunchKernelGGL(gla_tgemm, dim3(576), dim3(256), 0, stream, ws, ib);
    hipLaunchKernelGGL(gla_assemble, dim3((C_ * FH * FW + 255) / 256), dim3(256), 0, stream, out, ws, ib);
  }
}

// Round 5
// 394.412 us; speedup vs baseline: 1.4002x; 1.1273x over previous
//
#include <hip/hip_runtime.h>
#include <math.h>

// GlobalLocalAttention — mask-sparse pipeline, all GEMMs via bf16x2-split MFMA.
// R5: projections as MFMA GEMM (gla_qkv) + light per-patch softmax (gla_patch2);
//     transposed-conv output computed DIRECTLY as a 4-tap shifted GEMM (gla_out)
//     — eliminates T buffer, assemble, and the serialized per-batch loop.

constexpr int B_ = 4, C_ = 128, D_ = 16;
constexpr int FH = 96, FW = 96;
constexpr int Hh = 48, Wd = 48;
constexpr int L_ = Hh * Wd;           // 2304
constexpr int NEED_CAP = 384, HOLE_CAP = 320;
constexpr int KC = C_ * 9;            // 1152
constexpr int QKV_ROWS = 208;         // 0-15 q, 16-143 v, 144-191 pad, 192-207 k
constexpr int NQK = NEED_CAP * 9;     // 3456
constexpr float SCALE_ = 10.0f;
constexpr float EPS_ = 1e-4f;

typedef __attribute__((ext_vector_type(8))) short bf16x8;
typedef __attribute__((ext_vector_type(4))) float f32x4;
typedef __attribute__((ext_vector_type(4))) short s16x4;
typedef __attribute__((ext_vector_type(2))) unsigned short u16x2;

static __device__ __forceinline__ f32x4 mfma16(bf16x8 a, bf16x8 b, f32x4 c) {
  return __builtin_amdgcn_mfma_f32_16x16x32_bf16(a, b, c, 0, 0, 0);
}
static __device__ __forceinline__ unsigned short bf16_rne(float f) {
  unsigned u = __builtin_bit_cast(unsigned, f);
  unsigned r = (u + 0x7FFFu + ((u >> 16) & 1u)) >> 16;
  return (unsigned short)r;
}
static __device__ __forceinline__ float bf16f(unsigned short h) {
  unsigned u = ((unsigned)h) << 16;
  return __builtin_bit_cast(float, u);
}
static __device__ __forceinline__ void split2(float v, unsigned short& hi, unsigned short& lo) {
  hi = bf16_rne(v);
  lo = bf16_rne(v - bf16f(hi));
}

constexpr size_t A256(size_t v) { return (v + 255) & ~size_t(255); }
constexpr size_t OFF_META  = 0;
constexpr size_t OFF_MDS   = A256(OFF_META + 64 * 4);
constexpr size_t OFF_MP    = A256(OFF_MDS + (size_t)L_ * 4);
constexpr size_t OFF_MM    = A256(OFF_MP + (size_t)L_ * 9 * 4);
constexpr size_t OFF_ROWL  = A256(OFF_MM + (size_t)L_ * 4);
constexpr size_t OFF_NLIST = A256(OFF_ROWL + (size_t)L_ * 4);
constexpr size_t OFF_HLIST = A256(OFF_NLIST + (size_t)NEED_CAP * 4);
constexpr size_t OFF_NS1   = A256(OFF_HLIST + (size_t)HOLE_CAP * 4);
constexpr size_t OFF_NRAW  = A256(OFF_NS1 + (size_t)L_ * 4);
constexpr size_t OFF_WQVH  = A256(OFF_NRAW + (size_t)L_ * 4);                  // [192][128] bf16
constexpr size_t OFF_WQVL  = A256(OFF_WQVH + (size_t)192 * 128 * 2);
constexpr size_t OFF_WKH   = A256(OFF_WQVL + (size_t)192 * 128 * 2);           // [64][128]
constexpr size_t OFF_WKL   = A256(OFF_WKH + (size_t)64 * 128 * 2);
constexpr size_t OFF_FDSH  = A256(OFF_WKL + (size_t)64 * 128 * 2);             // bf16 [B][pos][c]
constexpr size_t OFF_FDSL  = A256(OFF_FDSH + (size_t)B_ * L_ * C_ * 2);
constexpr size_t OFF_BDSH  = A256(OFF_FDSL + (size_t)B_ * L_ * C_ * 2);
constexpr size_t OFF_BDSL  = A256(OFF_BDSH + (size_t)B_ * L_ * C_ * 2);
constexpr size_t OFF_QKV   = A256(OFF_BDSL + (size_t)B_ * L_ * C_ * 2);        // f32 [B][208][3456]
constexpr size_t OFF_WNH   = A256(OFF_QKV + (size_t)B_ * QKV_ROWS * NQK * 4);  // bf16 [B][384][1152]
constexpr size_t OFF_WNL   = A256(OFF_WNH + (size_t)B_ * NEED_CAP * KC * 2);
constexpr size_t OFF_SRAW  = A256(OFF_WNL + (size_t)B_ * NEED_CAP * KC * 2);   // f32 [B][384][L]
constexpr size_t OFF_PHT   = OFF_SRAW;                                          // alias (after fuse)
constexpr size_t OFF_PLT   = OFF_SRAW + (size_t)B_ * L_ * HOLE_CAP * 2;         // 5.9MB, 256-aligned
constexpr size_t OFF_SF    = A256(OFF_SRAW + (size_t)B_ * NEED_CAP * L_ * 4);  // f32 [B][320][L]
constexpr size_t OFF_RW3H  = A256(OFF_SF + (size_t)B_ * HOLE_CAP * L_ * 4);    // bf16 [B][4][128][1280]
constexpr size_t OFF_RW3L  = A256(OFF_RW3H + (size_t)B_ * 4 * C_ * 1280 * 2);
// total ~65 MB

// ---------------- mask prep + compaction + weight pack ----------------
__global__ __launch_bounds__(256) void gla_prep(const float* __restrict__ mask,
                                                const float* __restrict__ wq,
                                                const float* __restrict__ wk,
                                                const float* __restrict__ wv,
                                                char* __restrict__ ws)
{
  float* m_ds = (float*)(ws + OFF_MDS);
  float* m_p  = (float*)(ws + OFF_MP);
  float* mm   = (float*)(ws + OFF_MM);
  int* row_l  = (int*)(ws + OFF_ROWL);
  int* nlist  = (int*)(ws + OFF_NLIST);
  int* hlist  = (int*)(ws + OFF_HLIST);
  int* ns1    = (int*)(ws + OFF_NS1);
  int* nraw   = (int*)(ws + OFF_NRAW);
  int* meta   = (int*)(ws + OFF_META);
  const int t = threadIdx.x;

  // pack split-bf16 weight matrices: WQV = [wq(16); wv(128); 0(48)], WK = [wk(16); 0(48)]
  {
    unsigned short* qvh = (unsigned short*)(ws + OFF_WQVH);
    unsigned short* qvl = (unsigned short*)(ws + OFF_WQVL);
    unsigned short* kh  = (unsigned short*)(ws + OFF_WKH);
    unsigned short* kl  = (unsigned short*)(ws + OFF_WKL);
    for (int i = t; i < 192 * 128; i += 256) {
      int row = i >> 7, c = i & 127;
      float v = 0.f;
      if (row < 16) v = wq[row * C_ + c];
      else if (row < 144) v = wv[(row - 16) * C_ + c];
      unsigned short hi, lo; split2(v, hi, lo);
      qvh[i] = hi; qvl[i] = lo;
    }
    for (int i = t; i < 64 * 128; i += 256) {
      int row = i >> 7, c = i & 127;
      float v = (row < 16) ? wk[row * C_ + c] : 0.f;
      unsigned short hi, lo; split2(v, hi, lo);
      kh[i] = hi; kl[i] = lo;
    }
  }

  for (int l = t; l < L_; l += 256) {
    int y = l / Wd, x = l % Wd;
    m_ds[l] = mask[(size_t)(8 * y) * 384 + 8 * x];
  }
  __syncthreads();
  for (int l = t; l < L_; l += 256) {
    int y = l / Wd, x = l % Wd;
    bool all0 = true;
    for (int dy = 0; dy < 3; dy++)
      for (int dx = 0; dx < 3; dx++) {
        int sy = y + dy - 1, sx = x + dx - 1;
        float v = ((unsigned)sy < (unsigned)Hh && (unsigned)sx < (unsigned)Wd) ? m_ds[sy * Wd + sx] : 0.f;
        m_p[l * 9 + dy * 3 + dx] = v;
        if (v != 0.f) all0 = false;
      }
    mm[l] = all0 ? 1.f : 0.f;
    ns1[l] = 0; nraw[l] = 0; row_l[l] = -1;
  }
  __syncthreads();
  for (int l = t; l < L_; l += 256) {
    if (mm[l] == 1.f) {
      int i = l / Wd, j = l % Wd;
      int p2 = j * Hh + i;
      for (int k2 = -1; k2 <= 1; k2++) {
        int p2k = p2 + k2;
        if (p2k >= 0 && p2k < L_) {
          int j2 = p2k / Hh, i2 = p2k % Hh;
          ns1[i2 * Wd + j2] = 1;
        }
      }
    }
  }
  __syncthreads();
  for (int l = t; l < L_; l += 256) {
    if (ns1[l]) {
      for (int k1 = -1; k1 <= 1; k1++) {
        int l3 = l + k1;
        if (l3 >= 0 && l3 < L_) nraw[l3] = 1;
      }
    }
  }
  __syncthreads();
  int cN = 0, cH = 0;
  for (int q = 0; q < 9; q++) {
    int l = t * 9 + q;
    if (nraw[l]) cN++;
    if (mm[l] == 1.f) cH++;
  }
  __shared__ int sN[256], sH[256];
  sN[t] = cN; sH[t] = cH;
  __syncthreads();
  for (int off = 1; off < 256; off <<= 1) {
    int vN = (t >= off) ? sN[t - off] : 0;
    int vH = (t >= off) ? sH[t - off] : 0;
    __syncthreads();
    sN[t] += vN; sH[t] += vH;
    __syncthreads();
  }
  int bN = sN[t] - cN, bH = sH[t] - cH;
  for (int q = 0; q < 9; q++) {
    int l = t * 9 + q;
    if (nraw[l]) { if (bN < NEED_CAP) { nlist[bN] = l; row_l[l] = bN; } bN++; }
    if (mm[l] == 1.f) { if (bH < HOLE_CAP) { hlist[bH] = l; } bH++; }
  }
  if (t == 255) {
    meta[0] = sN[255] < NEED_CAP ? sN[255] : NEED_CAP;
    meta[1] = sH[255] < HOLE_CAP ? sH[255] : HOLE_CAP;
  }
}

// ---------------- downsample+transpose+split f,b -> [pos][c] bf16 hi/lo ----------------
__global__ __launch_bounds__(256) void gla_splitfb(const float* __restrict__ f, const float* __restrict__ b,
                                                   char* __restrict__ ws)
{
  const int y = blockIdx.x, ib = blockIdx.y, z = blockIdx.z;
  const float* src = z ? b : f;
  unsigned short* dsth = (unsigned short*)(ws + (z ? OFF_BDSH : OFF_FDSH));
  unsigned short* dstl = (unsigned short*)(ws + (z ? OFF_BDSL : OFF_FDSL));
  __shared__ float tile[48][130];
  const int t = threadIdx.x;
  for (int idx = t; idx < 48 * C_; idx += 256) {
    int x = idx % 48, c = idx / 48;
    tile[x][c] = src[(((size_t)ib * C_ + c) * FH + 2 * y) * FW + 2 * x];
  }
  __syncthreads();
  for (int i = 0; i < 12; i++) {
    int p = t + i * 256;
    int c2 = p & 63, x = p >> 6;
    float v0 = tile[x][c2 * 2], v1 = tile[x][c2 * 2 + 1];
    unsigned short h0, l0, h1, l1;
    split2(v0, h0, l0);
    split2(v1, h1, l1);
    size_t o = ((size_t)ib * L_ + (size_t)y * Wd + x) * C_ + c2 * 2;
    *(u16x2*)&dsth[o] = u16x2{h0, h1};
    *(u16x2*)&dstl[o] = u16x2{l0, l1};
  }
}

// ---------------- QKV projection GEMM (split-bf16 MFMA) ----------------
// QV: [wq;wv](192x128) x fi-cols ; K: wk(64x128) x wi-cols. N = 384*9 per batch.
__global__ __launch_bounds__(256) void gla_qkv(const float* __restrict__ bq, const float* __restrict__ bk,
                                               const float* __restrict__ bv, char* __restrict__ ws)
{
  const int* meta = (const int*)(ws + OFF_META);
  const int need = meta[0];
  int orig = blockIdx.x;
  int wg = (orig & 7) * 54 + (orig >> 3);   // 432 = 8*54
  bool isK = wg >= 324;
  int ib, mt, nt;
  if (!isK) { ib = wg / 81; int r2 = wg % 81; mt = r2 / 27; nt = r2 % 27; }
  else { int q2 = wg - 324; ib = q2 / 27; mt = 0; nt = q2 % 27; }
  const int m0 = mt * 64, n0 = nt * 128;
  const unsigned short* Ahg = (const unsigned short*)(ws + (isK ? OFF_WKH : OFF_WQVH));
  const unsigned short* Alg = (const unsigned short*)(ws + (isK ? OFF_WKL : OFF_WQVL));
  const unsigned short* Bhg = (const unsigned short*)(ws + (isK ? OFF_BDSH : OFF_FDSH)) + (size_t)ib * L_ * C_;
  const unsigned short* Blg = (const unsigned short*)(ws + (isK ? OFF_BDSL : OFF_FDSL)) + (size_t)ib * L_ * C_;
  const int* nlist = (const int*)(ws + OFF_NLIST);
  float* QKV = (float*)(ws + OFF_QKV) + (size_t)ib * QKV_ROWS * NQK;

  __shared__ short Ah[64][40], Al[64][40], Bh[128][40], Bl[128][40];
  const int tid = threadIdx.x;
  const int lane = tid & 63, w = tid >> 6;
  const int fr = lane & 15, kq = (lane >> 4) * 8;
  const int arow = tid & 63, aj = tid >> 6;
  const int bcol = tid & 127, bj = tid >> 7;

  const int col = n0 + bcol;
  const int r = col / 9, tap = col % 9;
  bool valid = (r < need);
  size_t bpos = 0;
  if (valid) {
    int l = nlist[r];
    int y = l / Wd, x = l % Wd;
    int sy = y + tap / 3 - 1, sx = x + tap % 3 - 1;
    valid = ((unsigned)sy < (unsigned)Hh) && ((unsigned)sx < (unsigned)Wd);
    if (valid) bpos = (size_t)(sy * Wd + sx) * C_;
  }

  f32x4 acc[4][2];
  #pragma unroll
  for (int mi = 0; mi < 4; mi++)
    #pragma unroll
    for (int ni = 0; ni < 2; ni++)
      #pragma unroll
      for (int q = 0; q < 4; q++) acc[mi][ni][q] = 0.f;

  const bf16x8 zz = {0, 0, 0, 0, 0, 0, 0, 0};
  bf16x8 rah, ral, rbh0, rbh1, rbl0, rbl1;
  auto load_step = [&](int s) {
    int k0 = s * 32;
    size_t aoff = (size_t)(m0 + arow) * 128 + k0 + aj * 8;
    rah = *(const bf16x8*)&Ahg[aoff];
    ral = *(const bf16x8*)&Alg[aoff];
    if (valid) {
      size_t boff = bpos + k0 + bj * 16;
      rbh0 = *(const bf16x8*)&Bhg[boff];
      rbh1 = *(const bf16x8*)&Bhg[boff + 8];
      rbl0 = *(const bf16x8*)&Blg[boff];
      rbl1 = *(const bf16x8*)&Blg[boff + 8];
    } else {
      rbh0 = zz; rbh1 = zz; rbl0 = zz; rbl1 = zz;
    }
  };

  load_step(0);
  for (int s = 0; s < 4; s++) {
    __syncthreads();
    *(bf16x8*)&Ah[arow][aj * 8] = rah;
    *(bf16x8*)&Al[arow][aj * 8] = ral;
    *(bf16x8*)&Bh[bcol][bj * 16] = rbh0;
    *(bf16x8*)&Bh[bcol][bj * 16 + 8] = rbh1;
    *(bf16x8*)&Bl[bcol][bj * 16] = rbl0;
    *(bf16x8*)&Bl[bcol][bj * 16 + 8] = rbl1;
    __syncthreads();
    if (s < 3) load_step(s + 1);
    bf16x8 a_h[4], a_l[4], b_h[2], b_l[2];
    #pragma unroll
    for (int mi = 0; mi < 4; mi++) {
      a_h[mi] = *(const bf16x8*)&Ah[mi * 16 + fr][kq];
      a_l[mi] = *(const bf16x8*)&Al[mi * 16 + fr][kq];
    }
    #pragma unroll
    for (int ni = 0; ni < 2; ni++) {
      b_h[ni] = *(const bf16x8*)&Bh[w * 32 + ni * 16 + fr][kq];
      b_l[ni] = *(const bf16x8*)&Bl[w * 32 + ni * 16 + fr][kq];
    }
    #pragma unroll
    for (int mi = 0; mi < 4; mi++)
      #pragma unroll
      for (int ni = 0; ni < 2; ni++) {
        acc[mi][ni] = mfma16(a_h[mi], b_h[ni], acc[mi][ni]);
        acc[mi][ni] = mfma16(a_h[mi], b_l[ni], acc[mi][ni]);
        acc[mi][ni] = mfma16(a_l[mi], b_h[ni], acc[mi][ni]);
      }
  }
  #pragma unroll
  for (int mi = 0; mi < 4; mi++)
    #pragma unroll
    for (int ni = 0; ni < 2; ni++) {
      int rowb = m0 + mi * 16 + (lane >> 4) * 4;
      int colg = n0 + w * 32 + ni * 16 + fr;
      #pragma unroll
      for (int q = 0; q < 4; q++) {
        int row = rowb + q;
        float v = acc[mi][ni][q];
        if (!isK) {
          float bias = row < 16 ? bq[row] : (row < 144 ? bv[row - 16] : 0.f);
          QKV[(size_t)row * NQK + colg] = v + bias;
        } else if (row < 16) {
          QKV[(size_t)(192 + row) * NQK + colg] = v + bk[row];
        }
      }
    }
}

// ---------------- per-patch attention softmax/blend/normalize -> wn ----------------
__global__ __launch_bounds__(128) void gla_patch2(const float* __restrict__ beta2p, char* __restrict__ ws)
{
  const int* meta = (const int*)(ws + OFF_META);
  int r = blockIdx.x;
  if (r >= meta[0]) return;
  int ib = blockIdx.y;
  const int* nlist = (const int*)(ws + OFF_NLIST);
  const float* m_p = (const float*)(ws + OFF_MP);
  const float* QKV = (const float*)(ws + OFF_QKV) + (size_t)ib * QKV_ROWS * NQK;
  const unsigned short* fdsh = (const unsigned short*)(ws + OFF_FDSH) + (size_t)ib * L_ * C_;
  const unsigned short* fdsl = (const unsigned short*)(ws + OFF_FDSL) + (size_t)ib * L_ * C_;
  unsigned short* wnh = (unsigned short*)(ws + OFF_WNH) + ((size_t)ib * NEED_CAP + r) * KC;
  unsigned short* wnl = (unsigned short*)(ws + OFF_WNL) + ((size_t)ib * NEED_CAP + r) * KC;

  __shared__ float qs[144], ks[144], att[81], mps[9], red[128];
  const int t = threadIdx.x;
  const int l = nlist[r];
  const int y = l / Wd, x = l % Wd;
  const int colb = r * 9;

  if (t < 9) mps[t] = m_p[l * 9 + t];
  for (int o = t; o < 288; o += 128) {
    if (o < 144) {           // q[n][d]
      int n = o / 16, d = o % 16;
      qs[o] = QKV[(size_t)d * NQK + colb + n];
    } else {                 // k[d][m]
      int o2 = o - 144;
      int d = o2 / 9, m = o2 % 9;
      ks[o2] = QKV[(size_t)(192 + d) * NQK + colb + m];
    }
  }
  __syncthreads();
  if (t < 81) {
    int n = t / 9, m = t % 9;
    float s = 0.f;
    #pragma unroll
    for (int d = 0; d < 16; d++) s += qs[n * 16 + d] * ks[d * 9 + m];
    att[t] = s * mps[m];
  }
  __syncthreads();
  if (t < 9) {
    float mx = -1e30f;
    for (int m = 0; m < 9; m++) mx = fmaxf(mx, att[t * 9 + m]);
    float e[9], sm = 0.f;
    for (int m = 0; m < 9; m++) { e[m] = expf(att[t * 9 + m] - mx); sm += e[m]; }
    float inv = 1.f / sm;
    for (int m = 0; m < 9; m++) att[t * 9 + m] = e[m] * inv;
  }
  __syncthreads();
  const int c = t;
  float vn[9], fi[9];
  #pragma unroll
  for (int n = 0; n < 9; n++) vn[n] = QKV[(size_t)(16 + c) * NQK + colb + n];
  #pragma unroll
  for (int m = 0; m < 9; m++) {
    int sy = y + m / 3 - 1, sx = x + m % 3 - 1;
    float v = 0.f;
    if ((unsigned)sy < (unsigned)Hh && (unsigned)sx < (unsigned)Wd) {
      size_t o = (size_t)(sy * Wd + sx) * C_ + c;
      v = bf16f(fdsh[o]) + bf16f(fdsl[o]);
    }
    fi[m] = v;
  }
  float beta2 = beta2p[0];
  float fm[9];
  #pragma unroll
  for (int m = 0; m < 9; m++) {
    float s = 0.f;
    #pragma unroll
    for (int n = 0; n < 9; n++) s += vn[n] * att[m * 9 + n];
    float mp = mps[m];
    fm[m] = beta2 * fi[m] * mp + (1.f - mp) * s;
  }
  float ss = 0.f;
  #pragma unroll
  for (int m = 0; m < 9; m++) ss += fm[m] * fm[m];
  red[t] = ss;
  __syncthreads();
  for (int off = 64; off > 0; off >>= 1) {
    if (t < off) red[t] += red[t + off];
    __syncthreads();
  }
  float inv = 1.f / fmaxf(sqrtf(red[0]), EPS_);
  #pragma unroll
  for (int m = 0; m < 9; m++) {
    unsigned short hi, lo;
    split2(fm[m] * inv, hi, lo);
    wnh[m * C_ + c] = hi;
    wnl[m * C_ + c] = lo;
  }
}

// ---------------- corr GEMM: BM=64 BN=128, reg-prefetch, XCD swizzle ----------------
__global__ __launch_bounds__(256) void gla_corr(char* __restrict__ ws)
{
  int orig = blockIdx.x;
  int wg = (orig & 7) * 54 + (orig >> 3);
  int xt = wg % 18;
  int rt = (wg / 18) % 6;
  int ib = wg / 108;
  const int r0 = rt * 64, x0 = xt * 128;

  const unsigned short* Ahg = (const unsigned short*)(ws + OFF_WNH) + (size_t)ib * NEED_CAP * KC;
  const unsigned short* Alg = (const unsigned short*)(ws + OFF_WNL) + (size_t)ib * NEED_CAP * KC;
  const unsigned short* fh = (const unsigned short*)(ws + OFF_FDSH) + (size_t)ib * L_ * C_;
  const unsigned short* fl = (const unsigned short*)(ws + OFF_FDSL) + (size_t)ib * L_ * C_;
  float* S = (float*)(ws + OFF_SRAW) + (size_t)ib * NEED_CAP * L_;

  __shared__ short Ah[64][40], Al[64][40], Bh[128][40], Bl[128][40];
  const int tid = threadIdx.x;
  const int lane = tid & 63, w = tid >> 6;
  const int fr = lane & 15, kq = (lane >> 4) * 8;
  const int arow = tid & 63, aj = tid >> 6;
  const int bcol = tid & 127, bj = tid >> 7;
  const int xg = x0 + bcol;
  const int aa = xg / Wd, bb = xg % Wd;

  f32x4 acc[4][2];
  #pragma unroll
  for (int mi = 0; mi < 4; mi++)
    #pragma unroll
    for (int ni = 0; ni < 2; ni++)
      #pragma unroll
      for (int q = 0; q < 4; q++) acc[mi][ni][q] = 0.f;

  const bf16x8 zz = {0, 0, 0, 0, 0, 0, 0, 0};
  bf16x8 rah, ral, rbh0, rbh1, rbl0, rbl1;

  auto load_step = [&](int s) {
    int tap = s >> 2, kc = s & 3;
    size_t aoff = (size_t)(r0 + arow) * KC + tap * 128 + kc * 32 + aj * 8;
    rah = *(const bf16x8*)&Ahg[aoff];
    ral = *(const bf16x8*)&Alg[aoff];
    int dyv = tap / 3, dxv = tap - 3 * dyv;
    int sy = aa + dyv - 1, sx = bb + dxv - 1;
    if (((unsigned)sy < (unsigned)Hh) & ((unsigned)sx < (unsigned)Wd)) {
      size_t bpos = (size_t)(sy * Wd + sx) * C_ + kc * 32 + bj * 16;
      rbh0 = *(const bf16x8*)&fh[bpos];
      rbh1 = *(const bf16x8*)&fh[bpos + 8];
      rbl0 = *(const bf16x8*)&fl[bpos];
      rbl1 = *(const bf16x8*)&fl[bpos + 8];
    } else {
      rbh0 = zz; rbh1 = zz; rbl0 = zz; rbl1 = zz;
    }
  };

  load_step(0);
  for (int s = 0; s < 36; s++) {
    __syncthreads();
    *(bf16x8*)&Ah[arow][aj * 8] = rah;
    *(bf16x8*)&Al[arow][aj * 8] = ral;
    *(bf16x8*)&Bh[bcol][bj * 16] = rbh0;
    *(bf16x8*)&Bh[bcol][bj * 16 + 8] = rbh1;
    *(bf16x8*)&Bl[bcol][bj * 16] = rbl0;
    *(bf16x8*)&Bl[bcol][bj * 16 + 8] = rbl1;
    __syncthreads();
    if (s < 35) load_step(s + 1);
    bf16x8 a_h[4], a_l[4], b_h[2], b_l[2];
    #pragma unroll
    for (int mi = 0; mi < 4; mi++) {
      a_h[mi] = *(const bf16x8*)&Ah[mi * 16 + fr][kq];
      a_l[mi] = *(const bf16x8*)&Al[mi * 16 + fr][kq];
    }
    #pragma unroll
    for (int ni = 0; ni < 2; ni++) {
      b_h[ni] = *(const bf16x8*)&Bh[w * 32 + ni * 16 + fr][kq];
      b_l[ni] = *(const bf16x8*)&Bl[w * 32 + ni * 16 + fr][kq];
    }
    #pragma unroll
    for (int mi = 0; mi < 4; mi++)
      #pragma unroll
      for (int ni = 0; ni < 2; ni++) {
        acc[mi][ni] = mfma16(a_h[mi], b_h[ni], acc[mi][ni]);
        acc[mi][ni] = mfma16(a_h[mi], b_l[ni], acc[mi][ni]);
        acc[mi][ni] = mfma16(a_l[mi], b_h[ni], acc[mi][ni]);
      }
  }
  #pragma unroll
  for (int mi = 0; mi < 4; mi++)
    #pragma unroll
    for (int ni = 0; ni < 2; ni++) {
      int row0 = r0 + mi * 16 + (lane >> 4) * 4;
      int col = x0 + w * 32 + ni * 16 + fr;
      #pragma unroll
      for (int q = 0; q < 4; q++)
        S[(size_t)(row0 + q) * L_ + col] = acc[mi][ni][q];
    }
}

// ---------------- fuse: two diagonal 3-taps in flattened index space ----------------
__global__ __launch_bounds__(256) void gla_fuse(char* __restrict__ ws)
{
  const int* meta = (const int*)(ws + OFF_META);
  int rh = blockIdx.y;
  if (rh >= meta[1]) return;
  int ib = blockIdx.z;
  const int* hlist = (const int*)(ws + OFF_HLIST);
  const int* row_l = (const int*)(ws + OFF_ROWL);
  const float* S = (const float*)(ws + OFF_SRAW) + (size_t)ib * NEED_CAP * L_;
  float* Sf = (float*)(ws + OFF_SF) + ((size_t)ib * HOLE_CAP + rh) * L_;
  int x = blockIdx.x * 256 + threadIdx.x;
  int l = hlist[rh];
  int i = l / Wd, j = l % Wd;
  int a = x / Wd, b = x % Wd;
  int p2 = j * Hh + i, q2 = b * Hh + a;
  float acc = 0.f;
  #pragma unroll
  for (int k2 = -1; k2 <= 1; k2++) {
    int p2k = p2 + k2, q2k = q2 + k2;
    if (p2k < 0 || p2k >= L_ || q2k < 0 || q2k >= L_) continue;
    int j2 = p2k / Hh, i2 = p2k % Hh;
    int b2 = q2k / Hh, a2 = q2k % Hh;
    int l1 = i2 * Wd + j2, x1 = a2 * Wd + b2;
    #pragma unroll
    for (int k1 = -1; k1 <= 1; k1++) {
      int l3 = l1 + k1, x3 = x1 + k1;
      if (l3 < 0 || l3 >= L_ || x3 < 0 || x3 >= L_) continue;
      int r = row_l[l3];
      if (r >= 0) acc += S[(size_t)r * L_ + x3];
    }
  }
  Sf[x] = acc;
}

// ---------------- column softmax -> split transposed P (aliased onto SRAW) ----------------
__global__ __launch_bounds__(256) void gla_softmax(char* __restrict__ ws)
{
  const int* meta = (const int*)(ws + OFF_META);
  const int hc = meta[1];
  const int ib = blockIdx.y;
  const int t = threadIdx.x;
  const int xl = t & 63, g = t >> 6;
  const int x0 = blockIdx.x * 64;
  const float* Sf = (const float*)(ws + OFF_SF) + (size_t)ib * HOLE_CAP * L_;
  unsigned short* Ph = (unsigned short*)(ws + OFF_PHT) + (size_t)ib * L_ * HOLE_CAP;
  unsigned short* Pl = (unsigned short*)(ws + OFF_PLT) + (size_t)ib * L_ * HOLE_CAP;
  __shared__ float red[4][64];
  __shared__ float smx[64], sinv[64];
  __shared__ short Th[64][72], Tl[64][72];
  const int x = x0 + xl;
  float mx = 0.f;
  for (int rh = g; rh < hc; rh += 4) mx = fmaxf(mx, SCALE_ * Sf[(size_t)rh * L_ + x]);
  red[g][xl] = mx;
  __syncthreads();
  mx = fmaxf(fmaxf(red[0][xl], red[1][xl]), fmaxf(red[2][xl], red[3][xl]));
  __syncthreads();
  float s = 0.f;
  for (int rh = g; rh < hc; rh += 4) s += expf(SCALE_ * Sf[(size_t)rh * L_ + x] - mx);
  red[g][xl] = s;
  __syncthreads();
  float den = (float)(L_ - hc) * expf(-mx) + red[0][xl] + red[1][xl] + red[2][xl] + red[3][xl];
  if (g == 0) { smx[xl] = mx; sinv[xl] = 1.f / den; }
  __syncthreads();
  for (int rh0 = 0; rh0 < HOLE_CAP; rh0 += 64) {
    for (int i = 0; i < 16; i++) {
      int idx = t + i * 256;
      int xl2 = idx & 63, rr = idx >> 6;
      int rh = rh0 + rr;
      float e = 0.f;
      if (rh < hc) e = expf(SCALE_ * Sf[(size_t)rh * L_ + x0 + xl2] - smx[xl2]) * sinv[xl2];
      unsigned short hi, lo;
      split2(e, hi, lo);
      Th[xl2][rr] = (short)hi;
      Tl[xl2][rr] = (short)lo;
    }
    __syncthreads();
    for (int i = 0; i < 4; i++) {
      int q = t + i * 256;
      int rq = q & 15, xl2 = q >> 4;
      size_t dst = (size_t)(x0 + xl2) * HOLE_CAP + rh0 + rq * 4;
      *(s16x4*)&Ph[dst] = *(const s16x4*)&Th[xl2][rq * 4];
      *(s16x4*)&Pl[dst] = *(const s16x4*)&Tl[xl2][rq * 4];
    }
    __syncthreads();
  }
}

// ---------------- pack raw_w per parity: RW3[ib][par][c][tap(dy,dx)*320+rh] ----------------
__global__ __launch_bounds__(256) void gla_packRW3(const float* __restrict__ b, char* __restrict__ ws)
{
  int idx = blockIdx.x * 256 + threadIdx.x;
  const int tot = B_ * 4 * C_ * 1280;
  if (idx >= tot) return;
  const int* meta = (const int*)(ws + OFF_META);
  const int* hlist = (const int*)(ws + OFF_HLIST);
  unsigned short* RH = (unsigned short*)(ws + OFF_RW3H);
  unsigned short* RL = (unsigned short*)(ws + OFF_RW3L);
  int kk = idx % 1280;
  int c = (idx / 1280) & 127;
  int par = (idx / (1280 * 128)) & 3;
  int ib = idx / (1280 * 128 * 4);
  int tap = kk / 320, rh = kk % 320;
  int dy = tap >> 1, dx = tap & 1;
  int pY = par >> 1, pX = par & 1;
  float v = 0.f;
  if (rh < meta[1]) {
    int l = hlist[rh];
    int yy = l / Wd, xx = l % Wd;
    int ty = 2 * dy + ((pY + 1) & 1);
    int tx = 2 * dx + ((pX + 1) & 1);
    int sy = 2 * yy - 1 + ty, sx = 2 * xx - 1 + tx;
    if ((unsigned)sy < (unsigned)FH && (unsigned)sx < (unsigned)FW)
      v = b[(((size_t)ib * C_ + c) * FH + sy) * FW + sx];
  }
  unsigned short hi, lo;
  split2(v, hi, lo);
  RH[idx] = hi;
  RL[idx] = lo;
}

// ---------------- output GEMM: out = 0.25 * RW3 . P(shifted 4-tap), direct write ----------------
__global__ __launch_bounds__(256) void gla_out(float* __restrict__ out, char* __restrict__ ws)
{
  const int* meta = (const int*)(ws + OFF_META);
  const int rsteps = (meta[1] + 31) >> 5;
  const int nsteps = 4 * rsteps;
  int orig = blockIdx.x;
  int wg = (orig & 7) * 72 + (orig >> 3);   // 576 = 8*72
  int nt = wg % 18;
  int mt = (wg / 18) % 2;
  int par = (wg / 36) % 4;
  int ib = wg / 144;
  const int m0 = mt * 64, n0 = nt * 128;
  const int pY = par >> 1, pX = par & 1;

  const unsigned short* Ahg = (const unsigned short*)(ws + OFF_RW3H) + ((size_t)(ib * 4 + par) * C_) * 1280;
  const unsigned short* Alg = (const unsigned short*)(ws + OFF_RW3L) + ((size_t)(ib * 4 + par) * C_) * 1280;
  const unsigned short* Ph = (const unsigned short*)(ws + OFF_PHT) + (size_t)ib * L_ * HOLE_CAP;
  const unsigned short* Pl = (const unsigned short*)(ws + OFF_PLT) + (size_t)ib * L_ * HOLE_CAP;

  __shared__ short Ah[64][40], Al[64][40], Bh[128][40], Bl[128][40];
  const int tid = threadIdx.x;
  const int lane = tid & 63, w = tid >> 6;
  const int fr = lane & 15, kq = (lane >> 4) * 8;
  const int arow = tid & 63, aj = tid >> 6;
  const int bcol = tid & 127, bj = tid >> 7;

  const int colg = n0 + bcol;
  const int Yh = colg / 48, Xh = colg % 48;
  size_t bpos[4];
  bool bval[4];
  #pragma unroll
  for (int j = 0; j < 4; j++) {
    int dy = j >> 1, dx = j & 1;
    int ay = Yh + pY - dy, bx = Xh + pX - dx;
    bval[j] = ((unsigned)ay < 48u) && ((unsigned)bx < 48u);
    bpos[j] = bval[j] ? (size_t)(ay * 48 + bx) * HOLE_CAP : 0;
  }

  f32x4 acc[4][2];
  #pragma unroll
  for (int mi = 0; mi < 4; mi++)
    #pragma unroll
    for (int ni = 0; ni < 2; ni++)
      #pragma unroll
      for (int q = 0; q < 4; q++) acc[mi][ni][q] = 0.f;

  const bf16x8 zz = {0, 0, 0, 0, 0, 0, 0, 0};
  bf16x8 rah, ral, rbh0, rbh1, rbl0, rbl1;
  auto load_step = [&](int s) {
    int tap = s / rsteps;
    int kr = (s - tap * rsteps) * 32;
    size_t aoff = (size_t)(m0 + arow) * 1280 + tap * 320 + kr + aj * 8;
    rah = *(const bf16x8*)&Ahg[aoff];
    ral = *(const bf16x8*)&Alg[aoff];
    if (bval[tap]) {
      size_t boff = bpos[tap] + kr + bj * 16;
      rbh0 = *(const bf16x8*)&Ph[boff];
      rbh1 = *(const bf16x8*)&Ph[boff + 8];
      rbl0 = *(const bf16x8*)&Pl[boff];
      rbl1 = *(const bf16x8*)&Pl[boff + 8];
    } else {
      rbh0 = zz; rbh1 = zz; rbl0 = zz; rbl1 = zz;
    }
  };

  load_step(0);
  for (int s = 0; s < nsteps; s++) {
    __syncthreads();
    *(bf16x8*)&Ah[arow][aj * 8] = rah;
    *(bf16x8*)&Al[arow][aj * 8] = ral;
    *(bf16x8*)&Bh[bcol][bj * 16] = rbh0;
    *(bf16x8*)&Bh[bcol][bj * 16 + 8] = rbh1;
    *(bf16x8*)&Bl[bcol][bj * 16] = rbl0;
    *(bf16x8*)&Bl[bcol][bj * 16 + 8] = rbl1;
    __syncthreads();
    if (s + 1 < nsteps) load_step(s + 1);
    bf16x8 a_h[4], a_l[4], b_h[2], b_l[2];
    #pragma unroll
    for (int mi = 0; mi < 4; mi++) {
      a_h[mi] = *(const bf16x8*)&Ah[mi * 16 + fr][kq];
      a_l[mi] = *(const bf16x8*)&Al[mi * 16 + fr][kq];
    }
    #pragma unroll
    for (int ni = 0; ni < 2; ni++) {
      b_h[ni] = *(const bf16x8*)&Bh[w * 32 + ni * 16 + fr][kq];
      b_l[ni] = *(const bf16x8*)&Bl[w * 32 + ni * 16 + fr][kq];
    }
    #pragma unroll
    for (int mi = 0; mi < 4; mi++)
      #pragma unroll
      for (int ni = 0; ni < 2; ni++) {
        acc[mi][ni] = mfma16(a_h[mi], b_h[ni], acc[mi][ni]);
        acc[mi][ni] = mfma16(a_h[mi], b_l[ni], acc[mi][ni]);
        acc[mi][ni] = mfma16(a_l[mi], b_h[ni], acc[mi][ni]);
      }
  }
  #pragma unroll
  for (int mi = 0; mi < 4; mi++)
    #pragma unroll
    for (int ni = 0; ni < 2; ni++) {
      int c0 = m0 + mi * 16 + (lane >> 4) * 4;
      int colg2 = n0 + w * 32 + ni * 16 + fr;
      int Yh2 = colg2 / 48, Xh2 = colg2 % 48;
      int Y = 2 * Yh2 + pY, X = 2 * Xh2 + pX;
      #pragma unroll
      for (int q = 0; q < 4; q++)
        out[(((size_t)ib * C_ + c0 + q) * FH + Y) * FW + X] = 0.25f * acc[mi][ni][q];
    }
}

extern "C" void kernel_launch(void* const* d_in, const int* in_sizes, int n_in,
                              void* d_out, int out_size, void* d_ws, size_t ws_size,
                              hipStream_t stream)
{
  (void)in_sizes; (void)n_in; (void)out_size; (void)ws_size;
  const float* f    = (const float*)d_in[0];
  const float* b    = (const float*)d_in[1];
  const float* mask = (const float*)d_in[2];
  const float* wq   = (const float*)d_in[3];
  const float* bq   = (const float*)d_in[4];
  const float* wk   = (const float*)d_in[5];
  const float* bk   = (const float*)d_in[6];
  const float* wv   = (const float*)d_in[7];
  const float* bv   = (const float*)d_in[8];
  const float* bt2  = (const float*)d_in[9];
  float* out = (float*)d_out;
  char* ws = (char*)d_ws;

  hipLaunchKernelGGL(gla_prep, dim3(1), dim3(256), 0, stream, mask, wq, wk, wv, ws);
  hipLaunchKernelGGL(gla_splitfb, dim3(Hh, B_, 2), dim3(256), 0, stream, f, b, ws);
  hipLaunchKernelGGL(gla_qkv, dim3(432), dim3(256), 0, stream, bq, bk, bv, ws);
  hipLaunchKernelGGL(gla_patch2, dim3(NEED_CAP, B_), dim3(128), 0, stream, bt2, ws);
  hipLaunchKernelGGL(gla_corr, dim3(432), dim3(256), 0, stream, ws);
  hipLaunchKernelGGL(gla_fuse, dim3(L_ / 256, HOLE_CAP, B_), dim3(256), 0, stream, ws);
  hipLaunchKernelGGL(gla_softmax, dim3(L_ / 64, B_), dim3(256), 0, stream, ws);
  hipLaunchKernelGGL(gla_packRW3, dim3((B_ * 4 * C_ * 1280 + 255) / 256), dim3(256), 0, stream, b, ws);
  hipLaunchKernelGGL(gla_out, dim3(576), dim3(256), 0, stream, out, ws);
}

// Round 6
// 351.721 us; speedup vs baseline: 1.5701x; 1.1214x over previous
//
#include <hip/hip_runtime.h>
#include <math.h>

// GlobalLocalAttention — mask-sparse pipeline, all GEMMs via bf16x2-split MFMA.
// R6: prep split into parallel kernels (wpack/maskA/scan) — kills the 88us 1-block kernel;
//     gla_out writes planar scratch (coalesced) + gla_inter assembles out (float2 stores)
//     — kills the stride-2 RMW write inflation. SF aliased over dead QKV/WN region.

constexpr int B_ = 4, C_ = 128, D_ = 16;
constexpr int FH = 96, FW = 96;
constexpr int Hh = 48, Wd = 48;
constexpr int L_ = Hh * Wd;           // 2304
constexpr int NEED_CAP = 384, HOLE_CAP = 320;
constexpr int KC = C_ * 9;            // 1152
constexpr int QKV_ROWS = 208;         // 0-15 q, 16-143 v, 144-191 pad, 192-207 k
constexpr int NQK = NEED_CAP * 9;     // 3456
constexpr float SCALE_ = 10.0f;
constexpr float EPS_ = 1e-4f;

typedef __attribute__((ext_vector_type(8))) short bf16x8;
typedef __attribute__((ext_vector_type(4))) float f32x4;
typedef __attribute__((ext_vector_type(4))) short s16x4;
typedef __attribute__((ext_vector_type(2))) unsigned short u16x2;

static __device__ __forceinline__ f32x4 mfma16(bf16x8 a, bf16x8 b, f32x4 c) {
  return __builtin_amdgcn_mfma_f32_16x16x32_bf16(a, b, c, 0, 0, 0);
}
static __device__ __forceinline__ unsigned short bf16_rne(float f) {
  unsigned u = __builtin_bit_cast(unsigned, f);
  unsigned r = (u + 0x7FFFu + ((u >> 16) & 1u)) >> 16;
  return (unsigned short)r;
}
static __device__ __forceinline__ float bf16f(unsigned short h) {
  unsigned u = ((unsigned)h) << 16;
  return __builtin_bit_cast(float, u);
}
static __device__ __forceinline__ void split2(float v, unsigned short& hi, unsigned short& lo) {
  hi = bf16_rne(v);
  lo = bf16_rne(v - bf16f(hi));
}

constexpr size_t A256(size_t v) { return (v + 255) & ~size_t(255); }
constexpr size_t OFF_META  = 0;
constexpr size_t OFF_MP    = A256(OFF_META + 64 * 4);                          // f32 [L][9]
constexpr size_t OFF_MM    = A256(OFF_MP + (size_t)L_ * 9 * 4);                // int [L]
constexpr size_t OFF_ROWL  = A256(OFF_MM + (size_t)L_ * 4);
constexpr size_t OFF_NLIST = A256(OFF_ROWL + (size_t)L_ * 4);
constexpr size_t OFF_HLIST = A256(OFF_NLIST + (size_t)NEED_CAP * 4);
constexpr size_t OFF_WQVH  = A256(OFF_HLIST + (size_t)HOLE_CAP * 4);           // [192][128] bf16
constexpr size_t OFF_WQVL  = A256(OFF_WQVH + (size_t)192 * 128 * 2);
constexpr size_t OFF_WKH   = A256(OFF_WQVL + (size_t)192 * 128 * 2);           // [64][128]
constexpr size_t OFF_WKL   = A256(OFF_WKH + (size_t)64 * 128 * 2);
constexpr size_t OFF_FDSH  = A256(OFF_WKL + (size_t)64 * 128 * 2);             // bf16 [B][pos][c]
constexpr size_t OFF_FDSL  = A256(OFF_FDSH + (size_t)B_ * L_ * C_ * 2);
constexpr size_t OFF_BDSH  = A256(OFF_FDSL + (size_t)B_ * L_ * C_ * 2);
constexpr size_t OFF_BDSL  = A256(OFF_BDSH + (size_t)B_ * L_ * C_ * 2);
constexpr size_t OFF_QKV   = A256(OFF_BDSL + (size_t)B_ * L_ * C_ * 2);        // f32 [B][208][3456]
constexpr size_t OFF_SF    = OFF_QKV;                                           // ALIAS: f32 [B][320][L] (QKV dead)
constexpr size_t OFF_WNH   = A256(OFF_QKV + (size_t)B_ * QKV_ROWS * NQK * 4);  // bf16 [B][384][1152]
constexpr size_t OFF_WNL   = A256(OFF_WNH + (size_t)B_ * NEED_CAP * KC * 2);
constexpr size_t OFF_SRAW  = A256(OFF_WNL + (size_t)B_ * NEED_CAP * KC * 2);   // f32 [B][384][L]
constexpr size_t OFF_PHT   = OFF_SRAW;                                          // ALIAS after fuse
constexpr size_t OFF_PLT   = OFF_SRAW + (size_t)B_ * L_ * HOLE_CAP * 2;
constexpr size_t OFF_RW3H  = A256(OFF_SRAW + (size_t)B_ * NEED_CAP * L_ * 4);  // bf16 [B][4][128][1280]
constexpr size_t OFF_RW3L  = A256(OFF_RW3H + (size_t)B_ * 4 * C_ * 1280 * 2);
constexpr size_t OFF_OUTS  = A256(OFF_RW3L + (size_t)B_ * 4 * C_ * 1280 * 2);  // f32 [B][4][128][L]
// total ~72 MB

// ---------------- weight pack (parallel) ----------------
__global__ __launch_bounds__(256) void gla_wpack(const float* __restrict__ wq, const float* __restrict__ wk,
                                                 const float* __restrict__ wv, char* __restrict__ ws)
{
  int i = blockIdx.x * 256 + threadIdx.x;
  unsigned short* qvh = (unsigned short*)(ws + OFF_WQVH);
  unsigned short* qvl = (unsigned short*)(ws + OFF_WQVL);
  unsigned short* kh  = (unsigned short*)(ws + OFF_WKH);
  unsigned short* kl  = (unsigned short*)(ws + OFF_WKL);
  if (i < 192 * 128) {
    int row = i >> 7, c = i & 127;
    float v = 0.f;
    if (row < 16) v = wq[row * C_ + c];
    else if (row < 144) v = wv[(row - 16) * C_ + c];
    unsigned short hi, lo; split2(v, hi, lo);
    qvh[i] = hi; qvl[i] = lo;
  } else if (i < 256 * 128) {
    int j = i - 192 * 128;
    int row = j >> 7, c = j & 127;
    float v = (row < 16) ? wk[row * C_ + c] : 0.f;
    unsigned short hi, lo; split2(v, hi, lo);
    kh[j] = hi; kl[j] = lo;
  }
}

// ---------------- mask patches (parallel, direct from mask) ----------------
__global__ __launch_bounds__(256) void gla_maskA(const float* __restrict__ mask, char* __restrict__ ws)
{
  int l = blockIdx.x * 256 + threadIdx.x;
  if (l >= L_) return;
  float* m_p = (float*)(ws + OFF_MP);
  int* mmi = (int*)(ws + OFF_MM);
  int y = l / Wd, x = l % Wd;
  bool all0 = true;
  #pragma unroll
  for (int dy = 0; dy < 3; dy++)
    #pragma unroll
    for (int dx = 0; dx < 3; dx++) {
      int sy = y + dy - 1, sx = x + dx - 1;
      float v = ((unsigned)sy < (unsigned)Hh && (unsigned)sx < (unsigned)Wd)
                ? mask[(size_t)(8 * sy) * 384 + 8 * sx] : 0.f;
      m_p[l * 9 + dy * 3 + dx] = v;
      if (v != 0.f) all0 = false;
    }
  mmi[l] = all0 ? 1 : 0;
}

// ---------------- compaction scan (1 block, LDS-resident dilations) ----------------
__global__ __launch_bounds__(256) void gla_scan(char* __restrict__ ws)
{
  const int* mmi = (const int*)(ws + OFF_MM);
  int* row_l = (int*)(ws + OFF_ROWL);
  int* nlist = (int*)(ws + OFF_NLIST);
  int* hlist = (int*)(ws + OFF_HLIST);
  int* meta  = (int*)(ws + OFF_META);
  __shared__ int ns1[L_], nraw[L_];
  __shared__ int sN[256], sH[256];
  const int t = threadIdx.x;
  for (int l = t; l < L_; l += 256) { ns1[l] = 0; nraw[l] = 0; }
  __syncthreads();
  for (int l = t; l < L_; l += 256) {
    if (mmi[l]) {
      int i = l / Wd, j = l % Wd;
      int p2 = j * Hh + i;
      for (int k2 = -1; k2 <= 1; k2++) {
        int p2k = p2 + k2;
        if (p2k >= 0 && p2k < L_) {
          int j2 = p2k / Hh, i2 = p2k % Hh;
          ns1[i2 * Wd + j2] = 1;
        }
      }
    }
  }
  __syncthreads();
  for (int l = t; l < L_; l += 256) {
    if (ns1[l]) {
      for (int k1 = -1; k1 <= 1; k1++) {
        int l3 = l + k1;
        if (l3 >= 0 && l3 < L_) nraw[l3] = 1;
      }
    }
  }
  __syncthreads();
  int cN = 0, cH = 0;
  for (int q = 0; q < 9; q++) {
    int l = t * 9 + q;
    if (nraw[l]) cN++;
    if (mmi[l]) cH++;
  }
  sN[t] = cN; sH[t] = cH;
  __syncthreads();
  for (int off = 1; off < 256; off <<= 1) {
    int vN = (t >= off) ? sN[t - off] : 0;
    int vH = (t >= off) ? sH[t - off] : 0;
    __syncthreads();
    sN[t] += vN; sH[t] += vH;
    __syncthreads();
  }
  int bN = sN[t] - cN, bH = sH[t] - cH;
  for (int q = 0; q < 9; q++) {
    int l = t * 9 + q;
    int rl = -1;
    if (nraw[l]) { if (bN < NEED_CAP) { nlist[bN] = l; rl = bN; } bN++; }
    row_l[l] = rl;
    if (mmi[l]) { if (bH < HOLE_CAP) { hlist[bH] = l; } bH++; }
  }
  if (t == 255) {
    meta[0] = sN[255] < NEED_CAP ? sN[255] : NEED_CAP;
    meta[1] = sH[255] < HOLE_CAP ? sH[255] : HOLE_CAP;
  }
}

// ---------------- downsample+transpose+split f,b -> [pos][c] bf16 hi/lo ----------------
__global__ __launch_bounds__(256) void gla_splitfb(const float* __restrict__ f, const float* __restrict__ b,
                                                   char* __restrict__ ws)
{
  const int y = blockIdx.x, ib = blockIdx.y, z = blockIdx.z;
  const float* src = z ? b : f;
  unsigned short* dsth = (unsigned short*)(ws + (z ? OFF_BDSH : OFF_FDSH));
  unsigned short* dstl = (unsigned short*)(ws + (z ? OFF_BDSL : OFF_FDSL));
  __shared__ float tile[48][130];
  const int t = threadIdx.x;
  for (int idx = t; idx < 48 * C_; idx += 256) {
    int x = idx % 48, c = idx / 48;
    tile[x][c] = src[(((size_t)ib * C_ + c) * FH + 2 * y) * FW + 2 * x];
  }
  __syncthreads();
  for (int i = 0; i < 12; i++) {
    int p = t + i * 256;
    int c2 = p & 63, x = p >> 6;
    float v0 = tile[x][c2 * 2], v1 = tile[x][c2 * 2 + 1];
    unsigned short h0, l0, h1, l1;
    split2(v0, h0, l0);
    split2(v1, h1, l1);
    size_t o = ((size_t)ib * L_ + (size_t)y * Wd + x) * C_ + c2 * 2;
    *(u16x2*)&dsth[o] = u16x2{h0, h1};
    *(u16x2*)&dstl[o] = u16x2{l0, l1};
  }
}

// ---------------- QKV projection GEMM (split-bf16 MFMA) ----------------
__global__ __launch_bounds__(256) void gla_qkv(const float* __restrict__ bq, const float* __restrict__ bk,
                                               const float* __restrict__ bv, char* __restrict__ ws)
{
  const int* meta = (const int*)(ws + OFF_META);
  const int need = meta[0];
  int orig = blockIdx.x;
  int wg = (orig & 7) * 54 + (orig >> 3);   // 432 = 8*54
  bool isK = wg >= 324;
  int ib, mt, nt;
  if (!isK) { ib = wg / 81; int r2 = wg % 81; mt = r2 / 27; nt = r2 % 27; }
  else { int q2 = wg - 324; ib = q2 / 27; mt = 0; nt = q2 % 27; }
  const int m0 = mt * 64, n0 = nt * 128;
  const unsigned short* Ahg = (const unsigned short*)(ws + (isK ? OFF_WKH : OFF_WQVH));
  const unsigned short* Alg = (const unsigned short*)(ws + (isK ? OFF_WKL : OFF_WQVL));
  const unsigned short* Bhg = (const unsigned short*)(ws + (isK ? OFF_BDSH : OFF_FDSH)) + (size_t)ib * L_ * C_;
  const unsigned short* Blg = (const unsigned short*)(ws + (isK ? OFF_BDSL : OFF_FDSL)) + (size_t)ib * L_ * C_;
  const int* nlist = (const int*)(ws + OFF_NLIST);
  float* QKV = (float*)(ws + OFF_QKV) + (size_t)ib * QKV_ROWS * NQK;

  __shared__ short Ah[64][40], Al[64][40], Bh[128][40], Bl[128][40];
  const int tid = threadIdx.x;
  const int lane = tid & 63, w = tid >> 6;
  const int fr = lane & 15, kq = (lane >> 4) * 8;
  const int arow = tid & 63, aj = tid >> 6;
  const int bcol = tid & 127, bj = tid >> 7;

  const int col = n0 + bcol;
  const int r = col / 9, tap = col % 9;
  bool valid = (r < need);
  size_t bpos = 0;
  if (valid) {
    int l = nlist[r];
    int y = l / Wd, x = l % Wd;
    int sy = y + tap / 3 - 1, sx = x + tap % 3 - 1;
    valid = ((unsigned)sy < (unsigned)Hh) && ((unsigned)sx < (unsigned)Wd);
    if (valid) bpos = (size_t)(sy * Wd + sx) * C_;
  }

  f32x4 acc[4][2];
  #pragma unroll
  for (int mi = 0; mi < 4; mi++)
    #pragma unroll
    for (int ni = 0; ni < 2; ni++)
      #pragma unroll
      for (int q = 0; q < 4; q++) acc[mi][ni][q] = 0.f;

  const bf16x8 zz = {0, 0, 0, 0, 0, 0, 0, 0};
  bf16x8 rah, ral, rbh0, rbh1, rbl0, rbl1;
  auto load_step = [&](int s) {
    int k0 = s * 32;
    size_t aoff = (size_t)(m0 + arow) * 128 + k0 + aj * 8;
    rah = *(const bf16x8*)&Ahg[aoff];
    ral = *(const bf16x8*)&Alg[aoff];
    if (valid) {
      size_t boff = bpos + k0 + bj * 16;
      rbh0 = *(const bf16x8*)&Bhg[boff];
      rbh1 = *(const bf16x8*)&Bhg[boff + 8];
      rbl0 = *(const bf16x8*)&Blg[boff];
      rbl1 = *(const bf16x8*)&Blg[boff + 8];
    } else {
      rbh0 = zz; rbh1 = zz; rbl0 = zz; rbl1 = zz;
    }
  };

  load_step(0);
  for (int s = 0; s < 4; s++) {
    __syncthreads();
    *(bf16x8*)&Ah[arow][aj * 8] = rah;
    *(bf16x8*)&Al[arow][aj * 8] = ral;
    *(bf16x8*)&Bh[bcol][bj * 16] = rbh0;
    *(bf16x8*)&Bh[bcol][bj * 16 + 8] = rbh1;
    *(bf16x8*)&Bl[bcol][bj * 16] = rbl0;
    *(bf16x8*)&Bl[bcol][bj * 16 + 8] = rbl1;
    __syncthreads();
    if (s < 3) load_step(s + 1);
    bf16x8 a_h[4], a_l[4], b_h[2], b_l[2];
    #pragma unroll
    for (int mi = 0; mi < 4; mi++) {
      a_h[mi] = *(const bf16x8*)&Ah[mi * 16 + fr][kq];
      a_l[mi] = *(const bf16x8*)&Al[mi * 16 + fr][kq];
    }
    #pragma unroll
    for (int ni = 0; ni < 2; ni++) {
      b_h[ni] = *(const bf16x8*)&Bh[w * 32 + ni * 16 + fr][kq];
      b_l[ni] = *(const bf16x8*)&Bl[w * 32 + ni * 16 + fr][kq];
    }
    #pragma unroll
    for (int mi = 0; mi < 4; mi++)
      #pragma unroll
      for (int ni = 0; ni < 2; ni++) {
        acc[mi][ni] = mfma16(a_h[mi], b_h[ni], acc[mi][ni]);
        acc[mi][ni] = mfma16(a_h[mi], b_l[ni], acc[mi][ni]);
        acc[mi][ni] = mfma16(a_l[mi], b_h[ni], acc[mi][ni]);
      }
  }
  #pragma unroll
  for (int mi = 0; mi < 4; mi++)
    #pragma unroll
    for (int ni = 0; ni < 2; ni++) {
      int rowb = m0 + mi * 16 + (lane >> 4) * 4;
      int colg = n0 + w * 32 + ni * 16 + fr;
      #pragma unroll
      for (int q = 0; q < 4; q++) {
        int row = rowb + q;
        float v = acc[mi][ni][q];
        if (!isK) {
          float bias = row < 16 ? bq[row] : (row < 144 ? bv[row - 16] : 0.f);
          QKV[(size_t)row * NQK + colg] = v + bias;
        } else if (row < 16) {
          QKV[(size_t)(192 + row) * NQK + colg] = v + bk[row];
        }
      }
    }
}

// ---------------- per-patch attention softmax/blend/normalize -> wn ----------------
__global__ __launch_bounds__(128) void gla_patch2(const float* __restrict__ beta2p, char* __restrict__ ws)
{
  const int* meta = (const int*)(ws + OFF_META);
  int r = blockIdx.x;
  if (r >= meta[0]) return;
  int ib = blockIdx.y;
  const int* nlist = (const int*)(ws + OFF_NLIST);
  const float* m_p = (const float*)(ws + OFF_MP);
  const float* QKV = (const float*)(ws + OFF_QKV) + (size_t)ib * QKV_ROWS * NQK;
  const unsigned short* fdsh = (const unsigned short*)(ws + OFF_FDSH) + (size_t)ib * L_ * C_;
  const unsigned short* fdsl = (const unsigned short*)(ws + OFF_FDSL) + (size_t)ib * L_ * C_;
  unsigned short* wnh = (unsigned short*)(ws + OFF_WNH) + ((size_t)ib * NEED_CAP + r) * KC;
  unsigned short* wnl = (unsigned short*)(ws + OFF_WNL) + ((size_t)ib * NEED_CAP + r) * KC;

  __shared__ float qs[144], ks[144], att[81], mps[9], red[128];
  const int t = threadIdx.x;
  const int l = nlist[r];
  const int y = l / Wd, x = l % Wd;
  const int colb = r * 9;

  if (t < 9) mps[t] = m_p[l * 9 + t];
  for (int o = t; o < 288; o += 128) {
    if (o < 144) {
      int n = o / 16, d = o % 16;
      qs[o] = QKV[(size_t)d * NQK + colb + n];
    } else {
      int o2 = o - 144;
      int d = o2 / 9, m = o2 % 9;
      ks[o2] = QKV[(size_t)(192 + d) * NQK + colb + m];
    }
  }
  __syncthreads();
  if (t < 81) {
    int n = t / 9, m = t % 9;
    float s = 0.f;
    #pragma unroll
    for (int d = 0; d < 16; d++) s += qs[n * 16 + d] * ks[d * 9 + m];
    att[t] = s * mps[m];
  }
  __syncthreads();
  if (t < 9) {
    float mx = -1e30f;
    for (int m = 0; m < 9; m++) mx = fmaxf(mx, att[t * 9 + m]);
    float e[9], sm = 0.f;
    for (int m = 0; m < 9; m++) { e[m] = expf(att[t * 9 + m] - mx); sm += e[m]; }
    float inv = 1.f / sm;
    for (int m = 0; m < 9; m++) att[t * 9 + m] = e[m] * inv;
  }
  __syncthreads();
  const int c = t;
  float vn[9], fi[9];
  #pragma unroll
  for (int n = 0; n < 9; n++) vn[n] = QKV[(size_t)(16 + c) * NQK + colb + n];
  #pragma unroll
  for (int m = 0; m < 9; m++) {
    int sy = y + m / 3 - 1, sx = x + m % 3 - 1;
    float v = 0.f;
    if ((unsigned)sy < (unsigned)Hh && (unsigned)sx < (unsigned)Wd) {
      size_t o = (size_t)(sy * Wd + sx) * C_ + c;
      v = bf16f(fdsh[o]) + bf16f(fdsl[o]);
    }
    fi[m] = v;
  }
  float beta2 = beta2p[0];
  float fm[9];
  #pragma unroll
  for (int m = 0; m < 9; m++) {
    float s = 0.f;
    #pragma unroll
    for (int n = 0; n < 9; n++) s += vn[n] * att[m * 9 + n];
    float mp = mps[m];
    fm[m] = beta2 * fi[m] * mp + (1.f - mp) * s;
  }
  float ss = 0.f;
  #pragma unroll
  for (int m = 0; m < 9; m++) ss += fm[m] * fm[m];
  red[t] = ss;
  __syncthreads();
  for (int off = 64; off > 0; off >>= 1) {
    if (t < off) red[t] += red[t + off];
    __syncthreads();
  }
  float inv = 1.f / fmaxf(sqrtf(red[0]), EPS_);
  #pragma unroll
  for (int m = 0; m < 9; m++) {
    unsigned short hi, lo;
    split2(fm[m] * inv, hi, lo);
    wnh[m * C_ + c] = hi;
    wnl[m * C_ + c] = lo;
  }
}

// ---------------- corr GEMM: BM=64 BN=128, reg-prefetch, XCD swizzle ----------------
__global__ __launch_bounds__(256) void gla_corr(char* __restrict__ ws)
{
  int orig = blockIdx.x;
  int wg = (orig & 7) * 54 + (orig >> 3);
  int xt = wg % 18;
  int rt = (wg / 18) % 6;
  int ib = wg / 108;
  const int r0 = rt * 64, x0 = xt * 128;

  const unsigned short* Ahg = (const unsigned short*)(ws + OFF_WNH) + (size_t)ib * NEED_CAP * KC;
  const unsigned short* Alg = (const unsigned short*)(ws + OFF_WNL) + (size_t)ib * NEED_CAP * KC;
  const unsigned short* fh = (const unsigned short*)(ws + OFF_FDSH) + (size_t)ib * L_ * C_;
  const unsigned short* fl = (const unsigned short*)(ws + OFF_FDSL) + (size_t)ib * L_ * C_;
  float* S = (float*)(ws + OFF_SRAW) + (size_t)ib * NEED_CAP * L_;

  __shared__ short Ah[64][40], Al[64][40], Bh[128][40], Bl[128][40];
  const int tid = threadIdx.x;
  const int lane = tid & 63, w = tid >> 6;
  const int fr = lane & 15, kq = (lane >> 4) * 8;
  const int arow = tid & 63, aj = tid >> 6;
  const int bcol = tid & 127, bj = tid >> 7;
  const int xg = x0 + bcol;
  const int aa = xg / Wd, bb = xg % Wd;

  f32x4 acc[4][2];
  #pragma unroll
  for (int mi = 0; mi < 4; mi++)
    #pragma unroll
    for (int ni = 0; ni < 2; ni++)
      #pragma unroll
      for (int q = 0; q < 4; q++) acc[mi][ni][q] = 0.f;

  const bf16x8 zz = {0, 0, 0, 0, 0, 0, 0, 0};
  bf16x8 rah, ral, rbh0, rbh1, rbl0, rbl1;

  auto load_step = [&](int s) {
    int tap = s >> 2, kc = s & 3;
    size_t aoff = (size_t)(r0 + arow) * KC + tap * 128 + kc * 32 + aj * 8;
    rah = *(const bf16x8*)&Ahg[aoff];
    ral = *(const bf16x8*)&Alg[aoff];
    int dyv = tap / 3, dxv = tap - 3 * dyv;
    int sy = aa + dyv - 1, sx = bb + dxv - 1;
    if (((unsigned)sy < (unsigned)Hh) & ((unsigned)sx < (unsigned)Wd)) {
      size_t bpos = (size_t)(sy * Wd + sx) * C_ + kc * 32 + bj * 16;
      rbh0 = *(const bf16x8*)&fh[bpos];
      rbh1 = *(const bf16x8*)&fh[bpos + 8];
      rbl0 = *(const bf16x8*)&fl[bpos];
      rbl1 = *(const bf16x8*)&fl[bpos + 8];
    } else {
      rbh0 = zz; rbh1 = zz; rbl0 = zz; rbl1 = zz;
    }
  };

  load_step(0);
  for (int s = 0; s < 36; s++) {
    __syncthreads();
    *(bf16x8*)&Ah[arow][aj * 8] = rah;
    *(bf16x8*)&Al[arow][aj * 8] = ral;
    *(bf16x8*)&Bh[bcol][bj * 16] = rbh0;
    *(bf16x8*)&Bh[bcol][bj * 16 + 8] = rbh1;
    *(bf16x8*)&Bl[bcol][bj * 16] = rbl0;
    *(bf16x8*)&Bl[bcol][bj * 16 + 8] = rbl1;
    __syncthreads();
    if (s < 35) load_step(s + 1);
    bf16x8 a_h[4], a_l[4], b_h[2], b_l[2];
    #pragma unroll
    for (int mi = 0; mi < 4; mi++) {
      a_h[mi] = *(const bf16x8*)&Ah[mi * 16 + fr][kq];
      a_l[mi] = *(const bf16x8*)&Al[mi * 16 + fr][kq];
    }
    #pragma unroll
    for (int ni = 0; ni < 2; ni++) {
      b_h[ni] = *(const bf16x8*)&Bh[w * 32 + ni * 16 + fr][kq];
      b_l[ni] = *(const bf16x8*)&Bl[w * 32 + ni * 16 + fr][kq];
    }
    #pragma unroll
    for (int mi = 0; mi < 4; mi++)
      #pragma unroll
      for (int ni = 0; ni < 2; ni++) {
        acc[mi][ni] = mfma16(a_h[mi], b_h[ni], acc[mi][ni]);
        acc[mi][ni] = mfma16(a_h[mi], b_l[ni], acc[mi][ni]);
        acc[mi][ni] = mfma16(a_l[mi], b_h[ni], acc[mi][ni]);
      }
  }
  #pragma unroll
  for (int mi = 0; mi < 4; mi++)
    #pragma unroll
    for (int ni = 0; ni < 2; ni++) {
      int row0 = r0 + mi * 16 + (lane >> 4) * 4;
      int col = x0 + w * 32 + ni * 16 + fr;
      #pragma unroll
      for (int q = 0; q < 4; q++)
        S[(size_t)(row0 + q) * L_ + col] = acc[mi][ni][q];
    }
}

// ---------------- fuse: two diagonal 3-taps in flattened index space ----------------
__global__ __launch_bounds__(256) void gla_fuse(char* __restrict__ ws)
{
  const int* meta = (const int*)(ws + OFF_META);
  int rh = blockIdx.y;
  if (rh >= meta[1]) return;
  int ib = blockIdx.z;
  const int* hlist = (const int*)(ws + OFF_HLIST);
  const int* row_l = (const int*)(ws + OFF_ROWL);
  const float* S = (const float*)(ws + OFF_SRAW) + (size_t)ib * NEED_CAP * L_;
  float* Sf = (float*)(ws + OFF_SF) + ((size_t)ib * HOLE_CAP + rh) * L_;
  int x = blockIdx.x * 256 + threadIdx.x;
  int l = hlist[rh];
  int i = l / Wd, j = l % Wd;
  int a = x / Wd, b = x % Wd;
  int p2 = j * Hh + i, q2 = b * Hh + a;
  float acc = 0.f;
  #pragma unroll
  for (int k2 = -1; k2 <= 1; k2++) {
    int p2k = p2 + k2, q2k = q2 + k2;
    if (p2k < 0 || p2k >= L_ || q2k < 0 || q2k >= L_) continue;
    int j2 = p2k / Hh, i2 = p2k % Hh;
    int b2 = q2k / Hh, a2 = q2k % Hh;
    int l1 = i2 * Wd + j2, x1 = a2 * Wd + b2;
    #pragma unroll
    for (int k1 = -1; k1 <= 1; k1++) {
      int l3 = l1 + k1, x3 = x1 + k1;
      if (l3 < 0 || l3 >= L_ || x3 < 0 || x3 >= L_) continue;
      int r = row_l[l3];
      if (r >= 0) acc += S[(size_t)r * L_ + x3];
    }
  }
  Sf[x] = acc;
}

// ---------------- column softmax -> split transposed P (aliased onto SRAW) ----------------
__global__ __launch_bounds__(256) void gla_softmax(char* __restrict__ ws)
{
  const int* meta = (const int*)(ws + OFF_META);
  const int hc = meta[1];
  const int ib = blockIdx.y;
  const int t = threadIdx.x;
  const int xl = t & 63, g = t >> 6;
  const int x0 = blockIdx.x * 64;
  const float* Sf = (const float*)(ws + OFF_SF) + (size_t)ib * HOLE_CAP * L_;
  unsigned short* Ph = (unsigned short*)(ws + OFF_PHT) + (size_t)ib * L_ * HOLE_CAP;
  unsigned short* Pl = (unsigned short*)(ws + OFF_PLT) + (size_t)ib * L_ * HOLE_CAP;
  __shared__ float red[4][64];
  __shared__ float smx[64], sinv[64];
  __shared__ short Th[64][72], Tl[64][72];
  const int x = x0 + xl;
  float mx = 0.f;
  for (int rh = g; rh < hc; rh += 4) mx = fmaxf(mx, SCALE_ * Sf[(size_t)rh * L_ + x]);
  red[g][xl] = mx;
  __syncthreads();
  mx = fmaxf(fmaxf(red[0][xl], red[1][xl]), fmaxf(red[2][xl], red[3][xl]));
  __syncthreads();
  float s = 0.f;
  for (int rh = g; rh < hc; rh += 4) s += expf(SCALE_ * Sf[(size_t)rh * L_ + x] - mx);
  red[g][xl] = s;
  __syncthreads();
  float den = (float)(L_ - hc) * expf(-mx) + red[0][xl] + red[1][xl] + red[2][xl] + red[3][xl];
  if (g == 0) { smx[xl] = mx; sinv[xl] = 1.f / den; }
  __syncthreads();
  for (int rh0 = 0; rh0 < HOLE_CAP; rh0 += 64) {
    for (int i = 0; i < 16; i++) {
      int idx = t + i * 256;
      int xl2 = idx & 63, rr = idx >> 6;
      int rh = rh0 + rr;
      float e = 0.f;
      if (rh < hc) e = expf(SCALE_ * Sf[(size_t)rh * L_ + x0 + xl2] - smx[xl2]) * sinv[xl2];
      unsigned short hi, lo;
      split2(e, hi, lo);
      Th[xl2][rr] = (short)hi;
      Tl[xl2][rr] = (short)lo;
    }
    __syncthreads();
    for (int i = 0; i < 4; i++) {
      int q = t + i * 256;
      int rq = q & 15, xl2 = q >> 4;
      size_t dst = (size_t)(x0 + xl2) * HOLE_CAP + rh0 + rq * 4;
      *(s16x4*)&Ph[dst] = *(const s16x4*)&Th[xl2][rq * 4];
      *(s16x4*)&Pl[dst] = *(const s16x4*)&Tl[xl2][rq * 4];
    }
    __syncthreads();
  }
}

// ---------------- pack raw_w per parity: RW3[ib][par][c][tap(dy,dx)*320+rh] ----------------
__global__ __launch_bounds__(256) void gla_packRW3(const float* __restrict__ b, char* __restrict__ ws)
{
  int idx = blockIdx.x * 256 + threadIdx.x;
  const int tot = B_ * 4 * C_ * 1280;
  if (idx >= tot) return;
  const int* meta = (const int*)(ws + OFF_META);
  const int* hlist = (const int*)(ws + OFF_HLIST);
  unsigned short* RH = (unsigned short*)(ws + OFF_RW3H);
  unsigned short* RL = (unsigned short*)(ws + OFF_RW3L);
  int kk = idx % 1280;
  int c = (idx / 1280) & 127;
  int par = (idx / (1280 * 128)) & 3;
  int ib = idx / (1280 * 128 * 4);
  int tap = kk / 320, rh = kk % 320;
  int dy = tap >> 1, dx = tap & 1;
  int pY = par >> 1, pX = par & 1;
  float v = 0.f;
  if (rh < meta[1]) {
    int l = hlist[rh];
    int yy = l / Wd, xx = l % Wd;
    int ty = 2 * dy + ((pY + 1) & 1);
    int tx = 2 * dx + ((pX + 1) & 1);
    int sy = 2 * yy - 1 + ty, sx = 2 * xx - 1 + tx;
    if ((unsigned)sy < (unsigned)FH && (unsigned)sx < (unsigned)FW)
      v = b[(((size_t)ib * C_ + c) * FH + sy) * FW + sx];
  }
  unsigned short hi, lo;
  split2(v, hi, lo);
  RH[idx] = hi;
  RL[idx] = lo;
}

// ---------------- output GEMM: OUTS[ib][par][c][pos] = 0.25 * RW3 . P(4-tap), BM=64 BN=64 ----------------
__global__ __launch_bounds__(256) void gla_out(char* __restrict__ ws)
{
  const int* meta = (const int*)(ws + OFF_META);
  const int rsteps = (meta[1] + 31) >> 5;
  const int nsteps = 4 * rsteps;
  int orig = blockIdx.x;
  int wg = (orig & 7) * 144 + (orig >> 3);   // 1152 = 8*144
  int nt = wg % 36;
  int rest = wg / 36;
  int mt = rest & 1;
  int par = (rest >> 1) & 3;
  int ib = rest >> 3;
  const int m0 = mt * 64, n0 = nt * 64;
  const int pY = par >> 1, pX = par & 1;

  const unsigned short* Ahg = (const unsigned short*)(ws + OFF_RW3H) + ((size_t)(ib * 4 + par) * C_) * 1280;
  const unsigned short* Alg = (const unsigned short*)(ws + OFF_RW3L) + ((size_t)(ib * 4 + par) * C_) * 1280;
  const unsigned short* Ph = (const unsigned short*)(ws + OFF_PHT) + (size_t)ib * L_ * HOLE_CAP;
  const unsigned short* Pl = (const unsigned short*)(ws + OFF_PLT) + (size_t)ib * L_ * HOLE_CAP;
  float* OUTS = (float*)(ws + OFF_OUTS) + (size_t)(ib * 4 + par) * C_ * L_;

  __shared__ short Ah[64][40], Al[64][40], Bh[64][40], Bl[64][40];
  const int tid = threadIdx.x;
  const int lane = tid & 63, w = tid >> 6;
  const int fr = lane & 15, kq = (lane >> 4) * 8;
  const int arow = tid & 63, aj = tid >> 6;
  const int bcol = tid & 63, bj = tid >> 6;

  const int colg = n0 + bcol;
  const int Yh = colg / 48, Xh = colg % 48;
  size_t bpos[4];
  bool bval[4];
  #pragma unroll
  for (int j = 0; j < 4; j++) {
    int dy = j >> 1, dx = j & 1;
    int ay = Yh + pY - dy, bx = Xh + pX - dx;
    bval[j] = ((unsigned)ay < 48u) && ((unsigned)bx < 48u);
    bpos[j] = bval[j] ? (size_t)(ay * 48 + bx) * HOLE_CAP : 0;
  }

  f32x4 acc[4];
  #pragma unroll
  for (int mi = 0; mi < 4; mi++)
    #pragma unroll
    for (int q = 0; q < 4; q++) acc[mi][q] = 0.f;

  const bf16x8 zz = {0, 0, 0, 0, 0, 0, 0, 0};
  bf16x8 rah, ral, rbh, rbl;
  auto load_step = [&](int s) {
    int tap = s / rsteps;
    int kr = (s - tap * rsteps) * 32;
    size_t aoff = (size_t)(m0 + arow) * 1280 + tap * 320 + kr + aj * 8;
    rah = *(const bf16x8*)&Ahg[aoff];
    ral = *(const bf16x8*)&Alg[aoff];
    if (bval[tap]) {
      size_t boff = bpos[tap] + kr + bj * 8;
      rbh = *(const bf16x8*)&Ph[boff];
      rbl = *(const bf16x8*)&Pl[boff];
    } else {
      rbh = zz; rbl = zz;
    }
  };

  load_step(0);
  for (int s = 0; s < nsteps; s++) {
    __syncthreads();
    *(bf16x8*)&Ah[arow][aj * 8] = rah;
    *(bf16x8*)&Al[arow][aj * 8] = ral;
    *(bf16x8*)&Bh[bcol][bj * 8] = rbh;
    *(bf16x8*)&Bl[bcol][bj * 8] = rbl;
    __syncthreads();
    if (s + 1 < nsteps) load_step(s + 1);
    bf16x8 b_h = *(const bf16x8*)&Bh[w * 16 + fr][kq];
    bf16x8 b_l = *(const bf16x8*)&Bl[w * 16 + fr][kq];
    #pragma unroll
    for (int mi = 0; mi < 4; mi++) {
      bf16x8 a_h = *(const bf16x8*)&Ah[mi * 16 + fr][kq];
      bf16x8 a_l = *(const bf16x8*)&Al[mi * 16 + fr][kq];
      acc[mi] = mfma16(a_h, b_h, acc[mi]);
      acc[mi] = mfma16(a_h, b_l, acc[mi]);
      acc[mi] = mfma16(a_l, b_h, acc[mi]);
    }
  }
  #pragma unroll
  for (int mi = 0; mi < 4; mi++) {
    int c0 = m0 + mi * 16 + (lane >> 4) * 4;
    int colpos = n0 + w * 16 + fr;
    #pragma unroll
    for (int q = 0; q < 4; q++)
      OUTS[(size_t)(c0 + q) * L_ + colpos] = 0.25f * acc[mi][q];
  }
}

// ---------------- interleave OUTS -> out (coalesced float2 stores) ----------------
__global__ __launch_bounds__(256) void gla_inter(float* __restrict__ out, const char* __restrict__ ws)
{
  int idx = blockIdx.x * 256 + threadIdx.x;
  if (idx >= B_ * C_ * FH * (FW / 2)) return;
  const float* OUTS = (const float*)(ws + OFF_OUTS);
  int Xh = idx % 48;
  int Y  = (idx / 48) % FH;
  int c  = (idx / (48 * FH)) % C_;
  int ib = idx / (48 * FH * C_);
  int pY = Y & 1, Yh = Y >> 1;
  size_t base = ((size_t)(ib * 4 + pY * 2) * C_ + c) * L_ + Yh * 48 + Xh;
  float2 o2;
  o2.x = OUTS[base];
  o2.y = OUTS[base + (size_t)C_ * L_];
  *(float2*)&out[(((size_t)ib * C_ + c) * FH + Y) * FW + 2 * Xh] = o2;
}

extern "C" void kernel_launch(void* const* d_in, const int* in_sizes, int n_in,
                              void* d_out, int out_size, void* d_ws, size_t ws_size,
                              hipStream_t stream)
{
  (void)in_sizes; (void)n_in; (void)out_size; (void)ws_size;
  const float* f    = (const float*)d_in[0];
  const float* b    = (const float*)d_in[1];
  const float* mask = (const float*)d_in[2];
  const float* wq   = (const float*)d_in[3];
  const float* bq   = (const float*)d_in[4];
  const float* wk   = (const float*)d_in[5];
  const float* bk   = (const float*)d_in[6];
  const float* wv   = (const float*)d_in[7];
  const float* bv   = (const float*)d_in[8];
  const float* bt2  = (const float*)d_in[9];
  float* out = (float*)d_out;
  char* ws = (char*)d_ws;

  hipLaunchKernelGGL(gla_wpack, dim3(128), dim3(256), 0, stream, wq, wk, wv, ws);
  hipLaunchKernelGGL(gla_maskA, dim3(9), dim3(256), 0, stream, mask, ws);
  hipLaunchKernelGGL(gla_scan, dim3(1), dim3(256), 0, stream, ws);
  hipLaunchKernelGGL(gla_splitfb, dim3(Hh, B_, 2), dim3(256), 0, stream, f, b, ws);
  hipLaunchKernelGGL(gla_qkv, dim3(432), dim3(256), 0, stream, bq, bk, bv, ws);
  hipLaunchKernelGGL(gla_patch2, dim3(NEED_CAP, B_), dim3(128), 0, stream, bt2, ws);
  hipLaunchKernelGGL(gla_corr, dim3(432), dim3(256), 0, stream, ws);
  hipLaunchKernelGGL(gla_fuse, dim3(L_ / 256, HOLE_CAP, B_), dim3(256), 0, stream, ws);
  hipLaunchKernelGGL(gla_softmax, dim3(L_ / 64, B_), dim3(256), 0, stream, ws);
  hipLaunchKernelGGL(gla_packRW3, dim3((B_ * 4 * C_ * 1280 + 255) / 256), dim3(256), 0, stream, b, ws);
  hipLaunchKernelGGL(gla_out, dim3(1152), dim3(256), 0, stream, ws);
  hipLaunchKernelGGL(gla_inter, dim3((B_ * C_ * FH * (FW / 2) + 255) / 256), dim3(256), 0, stream, out, ws);
}